// Round 3
// baseline (1984.204 us; speedup 1.0000x reference)
//
#include <hip/hip_runtime.h>
#include <hip/hip_bf16.h>
#include <math.h>

// babyGPT-50m forward: B=2 T=1024 V=50257 C=768 H=12 L=6 D=64
#define Bsz 2
#define Tt 1024
#define Vv 50257
#define Cc 768
#define Hh 12
#define Ll 6
#define NTOK (Bsz*Tt)
#define VPAD 50304

typedef __attribute__((ext_vector_type(8))) short bf16x8;
typedef __attribute__((ext_vector_type(8))) unsigned short u16x8;
typedef __attribute__((ext_vector_type(4))) unsigned short u16x4;
typedef __attribute__((ext_vector_type(4))) float f32x4;
typedef unsigned short u16;

static __device__ __forceinline__ u16 f2bf(float f){
  unsigned u = __float_as_uint(f);
  u += 0x7FFF + ((u >> 16) & 1);   // RNE
  return (u16)(u >> 16);
}
static __device__ __forceinline__ float bf2f(u16 h){
  return __uint_as_float(((unsigned)h) << 16);
}

// async global->LDS, 16B per lane; LDS dest is wave-uniform base + lane*16
#define GL16(g,l) __builtin_amdgcn_global_load_lds( \
    (const __attribute__((address_space(1))) void*)(g), \
    (__attribute__((address_space(3))) void*)(l), 16, 0, 0)

// ---------------- embedding: x = tok_emb[idx] + pos_emb (fp32) ----------------
__global__ void embed_kernel(const int* __restrict__ idx, const float* __restrict__ tok,
                             const float* __restrict__ pos, float* __restrict__ x){
  const int C4 = Cc/4;
  int i = blockIdx.x * 256 + threadIdx.x;
  if (i >= NTOK*C4) return;
  int tk = i / C4, c4 = i % C4;
  int row = idx[tk];
  int t = tk % Tt;
  float4 a = ((const float4*)tok)[(size_t)row*C4 + c4];
  float4 p = ((const float4*)pos)[(size_t)t*C4 + c4];
  float4 r; r.x=a.x+p.x; r.y=a.y+p.y; r.z=a.z+p.z; r.w=a.w+p.w;
  ((float4*)x)[i] = r;
}

// ---------------- layernorm: fp32 in -> bf16 out ----------------
__global__ void ln_kernel(const float* __restrict__ in, const float* __restrict__ g,
                          const float* __restrict__ bt, u16* __restrict__ out){
  int row = blockIdx.x, tid = threadIdx.x;
  const float* r = in + (size_t)row*Cc;
  float v0=r[tid], v1=r[tid+256], v2=r[tid+512];
  float s  = v0+v1+v2;
  float s2 = v0*v0+v1*v1+v2*v2;
  #pragma unroll
  for (int off=32; off; off>>=1){ s += __shfl_xor(s,off); s2 += __shfl_xor(s2,off); }
  __shared__ float red[8];
  int wid = tid >> 6;
  if ((tid & 63) == 0){ red[wid]=s; red[4+wid]=s2; }
  __syncthreads();
  float S  = red[0]+red[1]+red[2]+red[3];
  float S2 = red[4]+red[5]+red[6]+red[7];
  float mean = S * (1.0f/Cc);
  float var  = S2 * (1.0f/Cc) - mean*mean;
  float rstd = rsqrtf(var + 1e-5f);
  u16* o = out + (size_t)row*Cc;
  o[tid]     = f2bf((v0-mean)*rstd*g[tid]     + bt[tid]);
  o[tid+256] = f2bf((v1-mean)*rstd*g[tid+256] + bt[tid+256]);
  o[tid+512] = f2bf((v2-mean)*rstd*g[tid+512] + bt[tid+512]);
}

// ---- weight transpose+convert: fp32 [K][N] -> bf16 [Npad][K]; 64k x 32n tiles ----
__global__ void wtrans_kernel(const float* __restrict__ in, u16* __restrict__ out,
                              int K, int N, int Npad){
  __shared__ float t[64][33];
  int n0 = blockIdx.x*32, k0 = blockIdx.y*64;
  int tx = threadIdx.x, ty = threadIdx.y;   // block (32,8)
  #pragma unroll
  for (int i=0;i<8;i++){
    int k = k0+ty+i*8, n = n0+tx;
    t[ty+i*8][tx] = (n < N) ? in[(size_t)k*N + n] : 0.f;
  }
  __syncthreads();
  #pragma unroll
  for (int i=0;i<2;i++){
    int nl = i*16 + ty*2 + (tx>>4);
    int kl = (tx&15)*4;
    int n = n0 + nl;
    if (n < Npad){
      u16x4 pk;
      pk[0] = f2bf(t[kl+0][nl]); pk[1] = f2bf(t[kl+1][nl]);
      pk[2] = f2bf(t[kl+2][nl]); pk[3] = f2bf(t[kl+3][nl]);
      *(u16x4*)&out[(size_t)n*K + k0 + kl] = pk;   // 8B store, full-line packed
    }
  }
}

// ---------------- v-part of qkv -> vT[b,h][d][t] (bf16) ----------------
__global__ void vtrans_kernel(const u16* __restrict__ qkv, u16* __restrict__ vT){
  __shared__ u16 s[32][33];
  int bh = blockIdx.z; int b = bh/Hh, h = bh - b*Hh;
  int t0 = blockIdx.x*32, d0 = blockIdx.y*32;
  int tx=threadIdx.x, ty=threadIdx.y;       // block (32,8)
  #pragma unroll
  for (int i=0;i<4;i++)
    s[ty+i*8][tx] = qkv[(size_t)(b*Tt + t0+ty+i*8)*2304 + 1536 + h*64 + d0 + tx];
  __syncthreads();
  #pragma unroll
  for (int i=0;i<4;i++)
    vT[((size_t)bh*64 + d0+ty+i*8)*Tt + t0 + tx] = s[tx][ty+i*8];
}

// ---------------- bias concat [L][2304] ----------------
__global__ void bconcat_kernel(const float* __restrict__ bq, const float* __restrict__ bk,
                               const float* __restrict__ bv, float* __restrict__ o){
  int i = blockIdx.x*256 + threadIdx.x;
  if (i >= Ll*2304) return;
  int l = i/2304, j = i - l*2304;
  o[i] = (j < 768) ? bq[l*768+j] : (j < 1536) ? bk[l*768+j-768] : bv[l*768+j-1536];
}

// ---------------- causal row softmax over S (bf16, in place, normalized) ----------------
__global__ __launch_bounds__(256) void softmax_kernel(u16* __restrict__ S){
  __shared__ float red[8];
  int t = blockIdx.x & (Tt-1);
  u16* row = S + (size_t)blockIdx.x*Tt;
  int tid = threadIdx.x;
  int i0 = tid*4;
  ushort4 u = *(const ushort4*)&row[i0];
  float v0 = (i0   <= t) ? bf2f(u.x)*0.125f : -1e30f;
  float v1 = (i0+1 <= t) ? bf2f(u.y)*0.125f : -1e30f;
  float v2 = (i0+2 <= t) ? bf2f(u.z)*0.125f : -1e30f;
  float v3 = (i0+3 <= t) ? bf2f(u.w)*0.125f : -1e30f;
  float m = fmaxf(fmaxf(v0,v1), fmaxf(v2,v3));
  #pragma unroll
  for (int off=32; off; off>>=1) m = fmaxf(m, __shfl_xor(m, off));
  int wid = tid >> 6;
  if ((tid&63)==0) red[wid] = m;
  __syncthreads();
  m = fmaxf(fmaxf(red[0],red[1]), fmaxf(red[2],red[3]));
  float p0 = __expf(v0-m), p1 = __expf(v1-m), p2 = __expf(v2-m), p3 = __expf(v3-m);
  float s = p0+p1+p2+p3;
  #pragma unroll
  for (int off=32; off; off>>=1) s += __shfl_xor(s, off);
  if ((tid&63)==0) red[4+wid] = s;
  __syncthreads();
  float inv = 1.0f / (red[4]+red[5]+red[6]+red[7]);
  ushort4 w;
  w.x = f2bf(p0*inv); w.y = f2bf(p1*inv); w.z = f2bf(p2*inv); w.w = f2bf(p3*inv);
  *(ushort4*)&row[i0] = w;
}

// ---------------- MFMA GEMM, m97 structure + LDS-transposed epilogue ----------------
// MODE 0: plain (z=0, XCD-swizzled). MODE 1: S=QK^T (batched; skip above-diag).
// MODE 2: Y=P.V (batched; causal K bound; token-major C).
// ROWSCAN: fp32 out with arbitrary ldc (head) -> 256B-contiguous scalar row stores.
template<int MODE, int BN, bool BIAS, bool RESID, bool GELU, bool OUTBF, bool ROWSCAN>
__global__ __launch_bounds__(256) void mm_kernel(
    const u16* __restrict__ A, const u16* __restrict__ Bm,
    const float* __restrict__ bias, const float* __restrict__ resid,
    void* __restrict__ out, int N, int K, int lda, int ldb, int ldc)
{
  constexpr int FN   = (BN==128) ? 4 : 2;
  constexpr int CPW  = FN*16;          // cols per wave tile
  constexpr int ESTR = CPW + 4;        // epilogue LDS row stride (floats)
  constexpr int SMEM_STAGE = (128 + BN)*32*2;
  constexpr int SMEM_EPI   = 4*16*ESTR*4;
  constexpr int SMEMB = SMEM_STAGE > SMEM_EPI ? SMEM_STAGE : SMEM_EPI;
  __shared__ __align__(16) char smem[SMEMB];
  u16* As = (u16*)smem;
  u16* Bs = As + 128*32;

  int bx = blockIdx.x, by = blockIdx.y;
  if constexpr (MODE==0){              // bijective XCD swizzle (m204)
    int gx = gridDim.x;
    int nwg = gx * gridDim.y;
    int flat = by*gx + bx;
    int qq = nwg >> 3, rr = nwg & 7;
    int xcd = flat & 7, lid = flat >> 3;
    int swz = (xcd < rr) ? xcd*(qq+1) + lid : rr*(qq+1) + (xcd-rr)*qq + lid;
    bx = swz % gx; by = swz / gx;
  }
  int m0 = bx*128, n0 = by*BN;
  int z = blockIdx.z;
  size_t Ab=0, Bb=0, Cb=0; int kend = K;
  if constexpr (MODE==1){
    if (n0 > m0) return;                       // fully-masked causal block
    int b = z/Hh, h = z - b*Hh;
    Ab = (size_t)b*Tt*2304 + h*64;             // q rows
    Bb = Ab + 768;                             // k rows
    Cb = (size_t)z*Tt*Tt;
  } else if constexpr (MODE==2){
    Ab = (size_t)z*Tt*Tt;                      // P rows
    Bb = (size_t)z*64*Tt;                      // vT rows
    int b = z/Hh, h = z - b*Hh;
    Cb = (size_t)b*Tt*Cc + h*64;               // y token-major
    kend = (m0+128 < K) ? m0+128 : K;          // causal: P[t][s]=0 for s>t
  }
  int tid = threadIdx.x, lane = tid & 63, wid = tid >> 6;
  int wr = wid >> 1, wc = wid & 1;
  int r0 = wr*64, c0 = wc*(BN/2);
  int lrow = lane & 15, koff = (lane >> 4)*8;
  int sr = lane >> 2, sk = (lane & 3)*8;
  const u16* Ap = A + Ab + (size_t)(m0 + wid*32 + sr)*lda + sk;
  const u16* Bp = (BN==128) ? Bm + Bb + (size_t)(n0 + wid*32 + sr)*ldb + sk
                            : Bm + Bb + (size_t)(n0 + wid*16 + sr)*ldb + sk;
  u16* Al = As + wid*1024;
  u16* Bl = (BN==128) ? Bs + wid*1024 : Bs + wid*512;
  f32x4 acc[4][FN] = {};
  for (int k0 = 0; k0 < kend; k0 += 32){
    GL16(Ap + k0, Al);
    GL16(Ap + k0 + (size_t)16*lda, Al + 512);
    if constexpr (BN==128){
      GL16(Bp + k0, Bl);
      GL16(Bp + k0 + (size_t)16*ldb, Bl + 512);
    } else {
      GL16(Bp + k0, Bl);
    }
    __syncthreads();
    bf16x8 af[4], bfr[FN];
    #pragma unroll
    for (int m=0;m<4;m++) af[m] = *(const bf16x8*)&As[(r0 + m*16 + lrow)*32 + koff];
    #pragma unroll
    for (int n=0;n<FN;n++) bfr[n] = *(const bf16x8*)&Bs[(c0 + n*16 + lrow)*32 + koff];
    #pragma unroll
    for (int m=0;m<4;m++)
      #pragma unroll
      for (int n=0;n<FN;n++)
        acc[m][n] = __builtin_amdgcn_mfma_f32_16x16x32_bf16(af[m], bfr[n], acc[m][n], 0,0,0);
    __syncthreads();
  }

  // ---- epilogue: transpose through per-wave LDS tile, coalesced stores ----
  float* ebuf = (float*)smem + wid*16*ESTR;
  int er = lane >> 2;
  int ec = (lane & 3) * (CPW/4);
  #pragma unroll
  for (int m=0;m<4;m++){
    __syncthreads();   // protect WAR on smem (K-loop tiles / previous m readback)
    #pragma unroll
    for (int n=0;n<FN;n++)
      #pragma unroll
      for (int j=0;j<4;j++)
        ebuf[((lane>>4)*4+j)*ESTR + n*16 + (lane&15)] = acc[m][n][j];
    __syncthreads();
    if constexpr (ROWSCAN){
      // fp32 out, arbitrary ldc: one row of CPW floats per instruction
      #pragma unroll
      for (int rr2=0; rr2<16; rr2++){
        int gr2 = m0 + r0 + m*16 + rr2;
        int gc2 = n0 + c0 + lane;
        float v = ebuf[rr2*ESTR + lane];
        if (gc2 < N) ((float*)out)[Cb + (size_t)gr2*ldc + gc2] = v;
      }
    } else {
      int grow = m0 + r0 + m*16 + er;
      int gcol = n0 + c0 + ec;
      size_t rbase = Cb + (size_t)grow*ldc;
      if constexpr (OUTBF){
        u16 tmp[CPW/4];
        #pragma unroll
        for (int q=0;q<FN;q++){
          float4 v = *(const float4*)&ebuf[er*ESTR + ec + q*4];
          float f0=v.x, f1=v.y, f2=v.z, f3=v.w;
          if (BIAS){
            float4 b4 = *(const float4*)&bias[gcol + q*4];
            f0+=b4.x; f1+=b4.y; f2+=b4.z; f3+=b4.w;
          }
          if (GELU){
            f0 = 0.5f*f0*(1.f+erff(f0*0.70710678118654752f));
            f1 = 0.5f*f1*(1.f+erff(f1*0.70710678118654752f));
            f2 = 0.5f*f2*(1.f+erff(f2*0.70710678118654752f));
            f3 = 0.5f*f3*(1.f+erff(f3*0.70710678118654752f));
          }
          tmp[q*4+0]=f2bf(f0); tmp[q*4+1]=f2bf(f1);
          tmp[q*4+2]=f2bf(f2); tmp[q*4+3]=f2bf(f3);
        }
        #pragma unroll
        for (int s2=0; s2<CPW/32; s2++)
          *(u16x8*)&((u16*)out)[rbase + gcol + s2*8] = *(const u16x8*)&tmp[s2*8];
      } else {
        #pragma unroll
        for (int q=0;q<FN;q++){
          float4 v = *(const float4*)&ebuf[er*ESTR + ec + q*4];
          float f0=v.x, f1=v.y, f2=v.z, f3=v.w;
          if (BIAS){
            float4 b4 = *(const float4*)&bias[gcol + q*4];
            f0+=b4.x; f1+=b4.y; f2+=b4.z; f3+=b4.w;
          }
          if (GELU){
            f0 = 0.5f*f0*(1.f+erff(f0*0.70710678118654752f));
            f1 = 0.5f*f1*(1.f+erff(f1*0.70710678118654752f));
            f2 = 0.5f*f2*(1.f+erff(f2*0.70710678118654752f));
            f3 = 0.5f*f3*(1.f+erff(f3*0.70710678118654752f));
          }
          if (RESID){
            float4 r4 = *(const float4*)&resid[rbase + gcol + q*4];
            f0+=r4.x; f1+=r4.y; f2+=r4.z; f3+=r4.w;
          }
          float4 o4; o4.x=f0; o4.y=f1; o4.z=f2; o4.w=f3;
          *(float4*)&((float*)out)[rbase + gcol + q*4] = o4;
        }
      }
    }
  }
}

// ---------------- orchestration ----------------
extern "C" void kernel_launch(void* const* d_in, const int* in_sizes, int n_in,
                              void* d_out, int out_size, void* d_ws, size_t ws_size,
                              hipStream_t stream){
  const int*   idx  = (const int*)d_in[0];
  const float* tok  = (const float*)d_in[1];
  const float* pos  = (const float*)d_in[2];
  const float* ln1g = (const float*)d_in[3];
  const float* ln1b = (const float*)d_in[4];
  const float* Wq   = (const float*)d_in[5];
  const float* bq   = (const float*)d_in[6];
  const float* Wk   = (const float*)d_in[7];
  const float* bk   = (const float*)d_in[8];
  const float* Wv   = (const float*)d_in[9];
  const float* bv   = (const float*)d_in[10];
  const float* Wp   = (const float*)d_in[11];
  const float* bp   = (const float*)d_in[12];
  const float* ln2g = (const float*)d_in[13];
  const float* ln2b = (const float*)d_in[14];
  const float* Wf1  = (const float*)d_in[15];
  const float* bf1  = (const float*)d_in[16];
  const float* Wf2  = (const float*)d_in[17];
  const float* bf2  = (const float*)d_in[18];
  const float* lnfg = (const float*)d_in[19];
  const float* lnfb = (const float*)d_in[20];
  const float* headW= (const float*)d_in[21];
  float* outp = (float*)d_out;

  // workspace layout (~250 MB)
  char* w = (char*)d_ws;
  u16* wqkvT = (u16*)w;  w += (size_t)Ll*2304*768*2;   // [L][2304][768]
  u16* wpT   = (u16*)w;  w += (size_t)Ll*768*768*2;    // [L][768][768]
  u16* wf1T  = (u16*)w;  w += (size_t)Ll*3072*768*2;   // [L][3072][768]
  u16* wf2T  = (u16*)w;  w += (size_t)Ll*768*3072*2;   // [L][768][3072]
  u16* headT = (u16*)w;  w += (size_t)VPAD*768*2;      // [50304][768], zero-padded
  float* bqkv= (float*)w;w += (size_t)Ll*2304*4;
  float* x   = (float*)w;w += (size_t)NTOK*Cc*4;       // fp32 residual stream
  u16* h     = (u16*)w;  w += (size_t)NTOK*Cc*2;       // LN output (bf16)
  u16* qkv   = (u16*)w;  w += (size_t)NTOK*2304*2;
  u16* vT    = (u16*)w;  w += (size_t)Bsz*Hh*64*Tt*2;
  u16* S     = (u16*)w;  w += (size_t)Bsz*Hh*Tt*Tt*2;  // scores / probs (in place)
  u16* y     = (u16*)w;  w += (size_t)NTOK*Cc*2;
  u16* ff    = (u16*)w;  w += (size_t)NTOK*4*Cc*2;

  dim3 tb(32,8);
  for (int l=0;l<Ll;l++){
    wtrans_kernel<<<dim3(24,12), tb, 0, stream>>>(Wq+(size_t)l*Cc*Cc, wqkvT+(size_t)l*2304*768,          768, 768, 768);
    wtrans_kernel<<<dim3(24,12), tb, 0, stream>>>(Wk+(size_t)l*Cc*Cc, wqkvT+(size_t)l*2304*768+768*768,  768, 768, 768);
    wtrans_kernel<<<dim3(24,12), tb, 0, stream>>>(Wv+(size_t)l*Cc*Cc, wqkvT+(size_t)l*2304*768+1536*768, 768, 768, 768);
    wtrans_kernel<<<dim3(24,12), tb, 0, stream>>>(Wp+(size_t)l*Cc*Cc, wpT+(size_t)l*768*768,             768, 768, 768);
    wtrans_kernel<<<dim3(96,12), tb, 0, stream>>>(Wf1+(size_t)l*Cc*4*Cc, wf1T+(size_t)l*3072*768,        768, 3072, 3072);
    wtrans_kernel<<<dim3(24,48), tb, 0, stream>>>(Wf2+(size_t)l*4*Cc*Cc, wf2T+(size_t)l*768*3072,        3072, 768, 768);
  }
  wtrans_kernel<<<dim3(VPAD/32,12), tb, 0, stream>>>(headW, headT, 768, Vv, VPAD);
  bconcat_kernel<<<(Ll*2304+255)/256, 256, 0, stream>>>(bq, bk, bv, bqkv);

  embed_kernel<<<NTOK*(Cc/4)/256, 256, 0, stream>>>(idx, tok, pos, x);

  for (int l=0;l<Ll;l++){
    ln_kernel<<<NTOK, 256, 0, stream>>>(x, ln1g+l*Cc, ln1b+l*Cc, h);
    // qkv = h @ WqkvT + b   [2048][2304] bf16
    mm_kernel<0,128,true,false,false,true,false><<<dim3(16,18,1), 256, 0, stream>>>(
        h, wqkvT+(size_t)l*2304*768, bqkv+l*2304, nullptr, qkv, 2304, 768, 768, 768, 2304);
    vtrans_kernel<<<dim3(32,2,Bsz*Hh), tb, 0, stream>>>(qkv, vT);
    // S = q k^T (batched over b,h; causal blocks skipped)
    mm_kernel<1,128,false,false,false,true,false><<<dim3(8,8,Bsz*Hh), 256, 0, stream>>>(
        qkv, qkv, nullptr, nullptr, S, 1024, 64, 2304, 2304, 1024);
    softmax_kernel<<<Bsz*Hh*Tt, 256, 0, stream>>>(S);
    // y = P v  (batched; token-major bf16 out)
    mm_kernel<2,64,false,false,false,true,false><<<dim3(8,1,Bsz*Hh), 256, 0, stream>>>(
        S, vT, nullptr, nullptr, y, 64, 1024, 1024, 1024, 768);
    // x += y @ WpT + bp   (fp32 out, residual)
    mm_kernel<0,128,true,true,false,false,false><<<dim3(16,6,1), 256, 0, stream>>>(
        y, wpT+(size_t)l*768*768, bp+l*Cc, x, x, 768, 768, 768, 768, 768);
    ln_kernel<<<NTOK, 256, 0, stream>>>(x, ln2g+l*Cc, ln2b+l*Cc, h);
    // ff = gelu(h @ Wf1T + bf1)  bf16
    mm_kernel<0,128,true,false,true,true,false><<<dim3(16,24,1), 256, 0, stream>>>(
        h, wf1T+(size_t)l*3072*768, bf1+(size_t)l*4*Cc, nullptr, ff, 3072, 768, 768, 768, 3072);
    // x += ff @ Wf2T + bf2
    mm_kernel<0,128,true,true,false,false,false><<<dim3(16,6,1), 256, 0, stream>>>(
        ff, wf2T+(size_t)l*768*3072, bf2+l*Cc, x, x, 768, 3072, 3072, 3072, 768);
  }
  ln_kernel<<<NTOK, 256, 0, stream>>>(x, lnfg, lnfb, h);
  // head: fp32 out, ldc=50257 (odd) -> ROWSCAN epilogue
  mm_kernel<0,128,false,false,false,false,true><<<dim3(16,VPAD/128,1), 256, 0, stream>>>(
      h, headT, nullptr, nullptr, outp, Vv, 768, 768, 768, Vv);
}

// Round 4
// 1547.525 us; speedup vs baseline: 1.2822x; 1.2822x over previous
//
#include <hip/hip_runtime.h>
#include <hip/hip_bf16.h>
#include <math.h>

// babyGPT-50m forward: B=2 T=1024 V=50257 C=768 H=12 L=6 D=64
#define Bsz 2
#define Tt 1024
#define Vv 50257
#define Cc 768
#define Hh 12
#define Ll 6
#define NTOK (Bsz*Tt)
#define VPAD 50304

typedef __attribute__((ext_vector_type(8))) short bf16x8;
typedef __attribute__((ext_vector_type(8))) unsigned short u16x8;
typedef __attribute__((ext_vector_type(4))) unsigned short u16x4;
typedef __attribute__((ext_vector_type(4))) float f32x4;
typedef unsigned short u16;

static __device__ __forceinline__ u16 f2bf(float f){
  unsigned u = __float_as_uint(f);
  u += 0x7FFF + ((u >> 16) & 1);   // RNE
  return (u16)(u >> 16);
}
static __device__ __forceinline__ float bf2f(u16 h){
  return __uint_as_float(((unsigned)h) << 16);
}

// async global->LDS, 16B per lane; LDS dest is wave-uniform base + lane*16
#define GL16(g,l) __builtin_amdgcn_global_load_lds( \
    (const __attribute__((address_space(1))) void*)(g), \
    (__attribute__((address_space(3))) void*)(l), 16, 0, 0)

// ---------------- embedding: x = tok_emb[idx] + pos_emb (fp32) ----------------
__global__ void embed_kernel(const int* __restrict__ idx, const float* __restrict__ tok,
                             const float* __restrict__ pos, float* __restrict__ x){
  const int C4 = Cc/4;
  int i = blockIdx.x * 256 + threadIdx.x;
  if (i >= NTOK*C4) return;
  int tk = i / C4, c4 = i % C4;
  int row = idx[tk];
  int t = tk % Tt;
  float4 a = ((const float4*)tok)[(size_t)row*C4 + c4];
  float4 p = ((const float4*)pos)[(size_t)t*C4 + c4];
  float4 r; r.x=a.x+p.x; r.y=a.y+p.y; r.z=a.z+p.z; r.w=a.w+p.w;
  ((float4*)x)[i] = r;
}

// ---------------- layernorm: fp32 in -> bf16 out ----------------
__global__ void ln_kernel(const float* __restrict__ in, const float* __restrict__ g,
                          const float* __restrict__ bt, u16* __restrict__ out){
  int row = blockIdx.x, tid = threadIdx.x;
  const float* r = in + (size_t)row*Cc;
  float v0=r[tid], v1=r[tid+256], v2=r[tid+512];
  float s  = v0+v1+v2;
  float s2 = v0*v0+v1*v1+v2*v2;
  #pragma unroll
  for (int off=32; off; off>>=1){ s += __shfl_xor(s,off); s2 += __shfl_xor(s2,off); }
  __shared__ float red[8];
  int wid = tid >> 6;
  if ((tid & 63) == 0){ red[wid]=s; red[4+wid]=s2; }
  __syncthreads();
  float S  = red[0]+red[1]+red[2]+red[3];
  float S2 = red[4]+red[5]+red[6]+red[7];
  float mean = S * (1.0f/Cc);
  float var  = S2 * (1.0f/Cc) - mean*mean;
  float rstd = rsqrtf(var + 1e-5f);
  u16* o = out + (size_t)row*Cc;
  o[tid]     = f2bf((v0-mean)*rstd*g[tid]     + bt[tid]);
  o[tid+256] = f2bf((v1-mean)*rstd*g[tid+256] + bt[tid+256]);
  o[tid+512] = f2bf((v2-mean)*rstd*g[tid+512] + bt[tid+512]);
}

// ---- weight transpose+convert: fp32 [K][N] -> bf16 [Npad][K]; 64k x 32n tiles ----
__global__ void wtrans_kernel(const float* __restrict__ in, u16* __restrict__ out,
                              int K, int N, int Npad){
  __shared__ float t[64][33];
  int n0 = blockIdx.x*32, k0 = blockIdx.y*64;
  int tx = threadIdx.x, ty = threadIdx.y;   // block (32,8)
  #pragma unroll
  for (int i=0;i<8;i++){
    int k = k0+ty+i*8, n = n0+tx;
    t[ty+i*8][tx] = (n < N) ? in[(size_t)k*N + n] : 0.f;
  }
  __syncthreads();
  #pragma unroll
  for (int i=0;i<2;i++){
    int nl = i*16 + ty*2 + (tx>>4);
    int kl = (tx&15)*4;
    int n = n0 + nl;
    if (n < Npad){
      u16x4 pk;
      pk[0] = f2bf(t[kl+0][nl]); pk[1] = f2bf(t[kl+1][nl]);
      pk[2] = f2bf(t[kl+2][nl]); pk[3] = f2bf(t[kl+3][nl]);
      *(u16x4*)&out[(size_t)n*K + k0 + kl] = pk;
    }
  }
}

// ---------------- v-part of qkv -> vT[b,h][d][t] (bf16) ----------------
__global__ void vtrans_kernel(const u16* __restrict__ qkv, u16* __restrict__ vT){
  __shared__ u16 s[32][33];
  int bh = blockIdx.z; int b = bh/Hh, h = bh - b*Hh;
  int t0 = blockIdx.x*32, d0 = blockIdx.y*32;
  int tx=threadIdx.x, ty=threadIdx.y;       // block (32,8)
  #pragma unroll
  for (int i=0;i<4;i++)
    s[ty+i*8][tx] = qkv[(size_t)(b*Tt + t0+ty+i*8)*2304 + 1536 + h*64 + d0 + tx];
  __syncthreads();
  #pragma unroll
  for (int i=0;i<4;i++)
    vT[((size_t)bh*64 + d0+ty+i*8)*Tt + t0 + tx] = s[tx][ty+i*8];
}

// ---------------- bias concat [L][2304] ----------------
__global__ void bconcat_kernel(const float* __restrict__ bq, const float* __restrict__ bk,
                               const float* __restrict__ bv, float* __restrict__ o){
  int i = blockIdx.x*256 + threadIdx.x;
  if (i >= Ll*2304) return;
  int l = i/2304, j = i - l*2304;
  o[i] = (j < 768) ? bq[l*768+j] : (j < 1536) ? bk[l*768+j-768] : bv[l*768+j-1536];
}

// ---------------- flash attention ----------------
// grid (T/128, B*H), 256 thr (4 waves). Q,K from qkv; V^T from vT; out y bf16 token-major.
// QB=128 (32 rows/wave), KB=64. Online softmax fp32, P bf16 through swizzled LDS.
__global__ __launch_bounds__(256) void flash_kernel(
    const u16* __restrict__ qkv, const u16* __restrict__ vT, u16* __restrict__ y){
  __shared__ u16 Ks[2][64*64];     // [s][k], 128B rows, XOR-swizzled
  __shared__ u16 Vs[2][64*64];     // [d][s], 128B rows, XOR-swizzled
  __shared__ u16 Ps[4][32*64];     // per-wave [q][s], 128B rows, XOR-swizzled
  int bx = blockIdx.x;
  int bh = blockIdx.y; int b = bh/Hh, h = bh - b*Hh;
  int q0 = bx*128;
  int tid = threadIdx.x, lane = tid&63, wid = tid>>6;
  const size_t tokbase = (size_t)b*Tt;
  // Q fragments in registers (A-layout: row=lane&15, k=(lane>>4)*8+j)
  int arow = lane&15, akof = (lane>>4)*8;
  bf16x8 qa[2][2];
  #pragma unroll
  for (int mi=0;mi<2;mi++)
    #pragma unroll
    for (int ks=0;ks<2;ks++)
      qa[mi][ks] = *(const bf16x8*)&qkv[(tokbase + q0 + wid*32 + mi*16 + arow)*2304
                                        + h*64 + ks*32 + akof];
  // staging geometry: per GL16 a wave covers 8 rows of 128B; lane -> row lane>>3, byte (lane&7)*16
  int srow = lane>>3;
  int sbyte = ((lane&7)*16) ^ (srow<<4);      // pre-swizzled source byte-in-row
  const u16* kbase = qkv + tokbase*2304 + 768 + h*64;
  const u16* vbase = vT + (size_t)bh*64*Tt;
  auto STAGEKV = [&](int t, int bb){
    int j0 = t*64;
    #pragma unroll
    for (int c=0;c<2;c++){
      int r = wid*16 + c*8 + srow;
      GL16(kbase + (size_t)(j0 + r)*2304 + (sbyte>>1), &Ks[bb][(wid*16 + c*8)*64]);
      GL16(vbase + (size_t)r*Tt + j0 + (sbyte>>1),     &Vs[bb][(wid*16 + c*8)*64]);
    }
  };
  float m_r[2][4], l_r[2][4];
  f32x4 o_acc[2][4] = {};
  #pragma unroll
  for (int mi=0;mi<2;mi++)
    #pragma unroll
    for (int jj=0;jj<4;jj++){ m_r[mi][jj] = -1e30f; l_r[mi][jj] = 0.f; }

  int njt = 2*bx + 2;
  STAGEKV(0, 0);
  asm volatile("s_waitcnt vmcnt(0)" ::: "memory");
  __builtin_amdgcn_s_barrier();
  for (int t=0; t<njt; t++){
    int cur = t&1;
    if (t+1 < njt) STAGEKV(t+1, cur^1);
    int j0 = t*64;
    // ---- S = Q K^T ----
    f32x4 sacc[2][4] = {};
    #pragma unroll
    for (int ks=0;ks<2;ks++){
      bf16x8 kf[4];
      #pragma unroll
      for (int ni=0;ni<4;ni++){
        int s16 = ni*16 + (lane&15);
        int kb = (ks*64 + (lane>>4)*16) ^ ((s16&7)<<4);
        kf[ni] = *(const bf16x8*)((const char*)&Ks[cur][0] + s16*128 + kb);
      }
      #pragma unroll
      for (int mi=0;mi<2;mi++)
        #pragma unroll
        for (int ni=0;ni<4;ni++)
          sacc[mi][ni] = __builtin_amdgcn_mfma_f32_16x16x32_bf16(qa[mi][ks], kf[ni], sacc[mi][ni], 0,0,0);
    }
    // ---- scale + causal mask + online softmax ----
    float tmax[2][4];
    #pragma unroll
    for (int mi=0;mi<2;mi++)
      #pragma unroll
      for (int jj=0;jj<4;jj++) tmax[mi][jj] = -1e30f;
    #pragma unroll
    for (int mi=0;mi<2;mi++)
      #pragma unroll
      for (int ni=0;ni<4;ni++)
        #pragma unroll
        for (int jj=0;jj<4;jj++){
          float v = sacc[mi][ni][jj]*0.125f;
          int sg = j0 + ni*16 + (lane&15);
          int tg = q0 + wid*32 + mi*16 + (lane>>4)*4 + jj;
          v = (sg <= tg) ? v : -1e30f;
          sacc[mi][ni][jj] = v;
          tmax[mi][jj] = fmaxf(tmax[mi][jj], v);
        }
    #pragma unroll
    for (int mi=0;mi<2;mi++)
      #pragma unroll
      for (int jj=0;jj<4;jj++){
        float tm = tmax[mi][jj];
        tm = fmaxf(tm, __shfl_xor(tm,1)); tm = fmaxf(tm, __shfl_xor(tm,2));
        tm = fmaxf(tm, __shfl_xor(tm,4)); tm = fmaxf(tm, __shfl_xor(tm,8));
        float mn = fmaxf(m_r[mi][jj], tm);
        float al = __expf(m_r[mi][jj] - mn);
        m_r[mi][jj] = mn;
        l_r[mi][jj] *= al;
        tmax[mi][jj] = al;           // reuse as alpha
      }
    // P = exp(S - m), write bf16 to per-wave swizzled LDS; accumulate row sums
    float tsum[2][4] = {};
    #pragma unroll
    for (int mi=0;mi<2;mi++)
      #pragma unroll
      for (int ni=0;ni<4;ni++)
        #pragma unroll
        for (int jj=0;jj<4;jj++){
          float p = __expf(sacc[mi][ni][jj] - m_r[mi][jj]);
          tsum[mi][jj] += p;
          int pr = mi*16 + (lane>>4)*4 + jj;
          int pcb = (2*(ni*16 + (lane&15))) ^ ((pr&7)<<4);
          *(u16*)((char*)&Ps[wid][0] + pr*128 + pcb) = f2bf(p);
        }
    #pragma unroll
    for (int mi=0;mi<2;mi++)
      #pragma unroll
      for (int jj=0;jj<4;jj++){
        float ts = tsum[mi][jj];
        ts += __shfl_xor(ts,1); ts += __shfl_xor(ts,2);
        ts += __shfl_xor(ts,4); ts += __shfl_xor(ts,8);
        l_r[mi][jj] += ts;
        float al = tmax[mi][jj];
        #pragma unroll
        for (int ni2=0;ni2<4;ni2++) o_acc[mi][ni2][jj] *= al;
      }
    // ---- O += P V ----
    #pragma unroll
    for (int ks2=0;ks2<2;ks2++){
      bf16x8 pa[2], vf[4];
      #pragma unroll
      for (int mi=0;mi<2;mi++){
        int prr = mi*16 + (lane&15);
        int pb = (ks2*64 + (lane>>4)*16) ^ ((prr&7)<<4);
        pa[mi] = *(const bf16x8*)((const char*)&Ps[wid][0] + prr*128 + pb);
      }
      #pragma unroll
      for (int ni2=0;ni2<4;ni2++){
        int d16 = ni2*16 + (lane&15);
        int sb = (ks2*64 + (lane>>4)*16) ^ ((d16&7)<<4);
        vf[ni2] = *(const bf16x8*)((const char*)&Vs[cur][0] + d16*128 + sb);
      }
      #pragma unroll
      for (int mi=0;mi<2;mi++)
        #pragma unroll
        for (int ni2=0;ni2<4;ni2++)
          o_acc[mi][ni2] = __builtin_amdgcn_mfma_f32_16x16x32_bf16(pa[mi], vf[ni2], o_acc[mi][ni2], 0,0,0);
    }
    asm volatile("s_waitcnt vmcnt(0) lgkmcnt(0)" ::: "memory");
    __builtin_amdgcn_s_barrier();
  }
  // ---- normalize + store y (token-major bf16) ----
  #pragma unroll
  for (int mi=0;mi<2;mi++)
    #pragma unroll
    for (int jj=0;jj<4;jj++){
      float inv = 1.0f / l_r[mi][jj];
      int tok2 = q0 + wid*32 + mi*16 + (lane>>4)*4 + jj;
      size_t rb = (tokbase + tok2)*Cc + h*64;
      #pragma unroll
      for (int ni2=0;ni2<4;ni2++)
        y[rb + ni2*16 + (lane&15)] = f2bf(o_acc[mi][ni2][jj] * inv);
    }
}

// ---------------- MFMA GEMM: 128xBN tile, BK=32, 2-phase double-buffered ----------------
template<int BN, bool BIAS, bool RESID, bool GELU, bool OUTBF, bool ROWSCAN>
__global__ __launch_bounds__(256) void mm_kernel(
    const u16* __restrict__ A, const u16* __restrict__ Bm,
    const float* __restrict__ bias, const float* __restrict__ resid,
    void* __restrict__ out, int N, int K, int lda, int ldb, int ldc)
{
  constexpr int FN   = (BN==128) ? 4 : 2;
  constexpr int CPW  = FN*16;
  constexpr int ESTR = CPW + 4;
  constexpr int BHALF = (BN==128) ? 4096 : 2048;
  constexpr int SMEM_STAGE = 2*(128 + BN)*32*2;
  constexpr int SMEM_EPI   = 4*16*ESTR*4;
  constexpr int SMEMB = SMEM_STAGE > SMEM_EPI ? SMEM_STAGE : SMEM_EPI;
  __shared__ __align__(16) char smem[SMEMB];
  u16* As = (u16*)smem;                 // [2][128*32]
  u16* Bs = As + 2*128*32;              // [2][BN*32]

  int bx = blockIdx.x, by = blockIdx.y;
  {                                     // bijective XCD swizzle (m204)
    int gx = gridDim.x;
    int nwg = gx * gridDim.y;
    int flat = by*gx + bx;
    int qq = nwg >> 3, rr = nwg & 7;
    int xcd = flat & 7, lid = flat >> 3;
    int swz = (xcd < rr) ? xcd*(qq+1) + lid : rr*(qq+1) + (xcd-rr)*qq + lid;
    bx = swz % gx; by = swz / gx;
  }
  int m0 = bx*128, n0 = by*BN;
  int tid = threadIdx.x, lane = tid & 63, wid = tid >> 6;
  int wr = wid >> 1, wc = wid & 1;
  int r0 = wr*64, c0 = wc*(BN/2);
  int lrow = lane & 15, koff = (lane >> 4)*8;
  int sr = lane >> 2, sk = (lane & 3)*8;
  const u16* Ap = A + (size_t)(m0 + wid*32 + sr)*lda + sk;
  const u16* Bp = (BN==128) ? Bm + (size_t)(n0 + wid*32 + sr)*ldb + sk
                            : Bm + (size_t)(n0 + wid*16 + sr)*ldb + sk;
  int nt = K/32;
  auto STAGE = [&](int t, int bb){
    int kk = t*32;
    u16* Al = As + bb*4096 + wid*1024;
    GL16(Ap + kk, Al);
    GL16(Ap + kk + (size_t)16*lda, Al + 512);
    if constexpr (BN==128){
      u16* Bl = Bs + bb*4096 + wid*1024;
      GL16(Bp + kk, Bl);
      GL16(Bp + kk + (size_t)16*ldb, Bl + 512);
    } else {
      u16* Bl = Bs + bb*2048 + wid*512;
      GL16(Bp + kk, Bl);
    }
  };
  f32x4 acc[4][FN] = {};
  STAGE(0, 0);
  asm volatile("s_waitcnt vmcnt(0)" ::: "memory");
  __builtin_amdgcn_s_barrier();
  for (int t = 0; t < nt; t++){
    int cur = t & 1;
    if (t+1 < nt) STAGE(t+1, cur^1);
    const u16* Ab2 = As + cur*4096;
    const u16* Bb2 = Bs + cur*BHALF;
    bf16x8 af[4], bfr[FN];
    #pragma unroll
    for (int m=0;m<4;m++) af[m] = *(const bf16x8*)&Ab2[(r0 + m*16 + lrow)*32 + koff];
    #pragma unroll
    for (int n=0;n<FN;n++) bfr[n] = *(const bf16x8*)&Bb2[(c0 + n*16 + lrow)*32 + koff];
    #pragma unroll
    for (int m=0;m<4;m++)
      #pragma unroll
      for (int n=0;n<FN;n++)
        acc[m][n] = __builtin_amdgcn_mfma_f32_16x16x32_bf16(af[m], bfr[n], acc[m][n], 0,0,0);
    asm volatile("s_waitcnt vmcnt(0) lgkmcnt(0)" ::: "memory");
    __builtin_amdgcn_s_barrier();
  }

  // ---- epilogue: transpose through per-wave LDS tile, coalesced stores ----
  float* ebuf = (float*)smem + wid*16*ESTR;
  int er = lane >> 2;
  int ec = (lane & 3) * (CPW/4);
  #pragma unroll
  for (int m=0;m<4;m++){
    __syncthreads();
    #pragma unroll
    for (int n=0;n<FN;n++)
      #pragma unroll
      for (int j=0;j<4;j++)
        ebuf[((lane>>4)*4+j)*ESTR + n*16 + (lane&15)] = acc[m][n][j];
    __syncthreads();
    if constexpr (ROWSCAN){
      #pragma unroll
      for (int rr2=0; rr2<16; rr2++){
        int gr2 = m0 + r0 + m*16 + rr2;
        int gc2 = n0 + c0 + lane;
        float v = ebuf[rr2*ESTR + lane];
        if (gc2 < N) ((float*)out)[(size_t)gr2*ldc + gc2] = v;
      }
    } else {
      int grow = m0 + r0 + m*16 + er;
      int gcol = n0 + c0 + ec;
      size_t rbase = (size_t)grow*ldc;
      if constexpr (OUTBF){
        u16 tmp[CPW/4];
        #pragma unroll
        for (int q=0;q<FN;q++){
          float4 v = *(const float4*)&ebuf[er*ESTR + ec + q*4];
          float f0=v.x, f1=v.y, f2=v.z, f3=v.w;
          if (BIAS){
            float4 b4 = *(const float4*)&bias[gcol + q*4];
            f0+=b4.x; f1+=b4.y; f2+=b4.z; f3+=b4.w;
          }
          if (GELU){
            f0 = 0.5f*f0*(1.f+erff(f0*0.70710678118654752f));
            f1 = 0.5f*f1*(1.f+erff(f1*0.70710678118654752f));
            f2 = 0.5f*f2*(1.f+erff(f2*0.70710678118654752f));
            f3 = 0.5f*f3*(1.f+erff(f3*0.70710678118654752f));
          }
          tmp[q*4+0]=f2bf(f0); tmp[q*4+1]=f2bf(f1);
          tmp[q*4+2]=f2bf(f2); tmp[q*4+3]=f2bf(f3);
        }
        #pragma unroll
        for (int s2=0; s2<CPW/32; s2++)
          *(u16x8*)&((u16*)out)[rbase + gcol + s2*8] = *(const u16x8*)&tmp[s2*8];
        if constexpr (CPW==32){}  // BN=64: CPW/32==1 handled above
      } else {
        #pragma unroll
        for (int q=0;q<FN;q++){
          float4 v = *(const float4*)&ebuf[er*ESTR + ec + q*4];
          float f0=v.x, f1=v.y, f2=v.z, f3=v.w;
          if (BIAS){
            float4 b4 = *(const float4*)&bias[gcol + q*4];
            f0+=b4.x; f1+=b4.y; f2+=b4.z; f3+=b4.w;
          }
          if (GELU){
            f0 = 0.5f*f0*(1.f+erff(f0*0.70710678118654752f));
            f1 = 0.5f*f1*(1.f+erff(f1*0.70710678118654752f));
            f2 = 0.5f*f2*(1.f+erff(f2*0.70710678118654752f));
            f3 = 0.5f*f3*(1.f+erff(f3*0.70710678118654752f));
          }
          if (RESID){
            float4 r4 = *(const float4*)&resid[rbase + gcol + q*4];
            f0+=r4.x; f1+=r4.y; f2+=r4.z; f3+=r4.w;
          }
          float4 o4; o4.x=f0; o4.y=f1; o4.z=f2; o4.w=f3;
          *(float4*)&((float*)out)[rbase + gcol + q*4] = o4;
        }
      }
    }
  }
}

// ---------------- orchestration ----------------
extern "C" void kernel_launch(void* const* d_in, const int* in_sizes, int n_in,
                              void* d_out, int out_size, void* d_ws, size_t ws_size,
                              hipStream_t stream){
  const int*   idx  = (const int*)d_in[0];
  const float* tok  = (const float*)d_in[1];
  const float* pos  = (const float*)d_in[2];
  const float* ln1g = (const float*)d_in[3];
  const float* ln1b = (const float*)d_in[4];
  const float* Wq   = (const float*)d_in[5];
  const float* bq   = (const float*)d_in[6];
  const float* Wk   = (const float*)d_in[7];
  const float* bk   = (const float*)d_in[8];
  const float* Wv   = (const float*)d_in[9];
  const float* bv   = (const float*)d_in[10];
  const float* Wp   = (const float*)d_in[11];
  const float* bp   = (const float*)d_in[12];
  const float* ln2g = (const float*)d_in[13];
  const float* ln2b = (const float*)d_in[14];
  const float* Wf1  = (const float*)d_in[15];
  const float* bf1  = (const float*)d_in[16];
  const float* Wf2  = (const float*)d_in[17];
  const float* bf2  = (const float*)d_in[18];
  const float* lnfg = (const float*)d_in[19];
  const float* lnfb = (const float*)d_in[20];
  const float* headW= (const float*)d_in[21];
  float* outp = (float*)d_out;

  char* w = (char*)d_ws;
  u16* wqkvT = (u16*)w;  w += (size_t)Ll*2304*768*2;
  u16* wpT   = (u16*)w;  w += (size_t)Ll*768*768*2;
  u16* wf1T  = (u16*)w;  w += (size_t)Ll*3072*768*2;
  u16* wf2T  = (u16*)w;  w += (size_t)Ll*768*3072*2;
  u16* headT = (u16*)w;  w += (size_t)VPAD*768*2;
  float* bqkv= (float*)w;w += (size_t)Ll*2304*4;
  float* x   = (float*)w;w += (size_t)NTOK*Cc*4;
  u16* h     = (u16*)w;  w += (size_t)NTOK*Cc*2;
  u16* qkv   = (u16*)w;  w += (size_t)NTOK*2304*2;
  u16* vT    = (u16*)w;  w += (size_t)Bsz*Hh*64*Tt*2;
  u16* y     = (u16*)w;  w += (size_t)NTOK*Cc*2;
  u16* ff    = (u16*)w;  w += (size_t)NTOK*4*Cc*2;

  dim3 tb(32,8);
  for (int l=0;l<Ll;l++){
    wtrans_kernel<<<dim3(24,12), tb, 0, stream>>>(Wq+(size_t)l*Cc*Cc, wqkvT+(size_t)l*2304*768,          768, 768, 768);
    wtrans_kernel<<<dim3(24,12), tb, 0, stream>>>(Wk+(size_t)l*Cc*Cc, wqkvT+(size_t)l*2304*768+768*768,  768, 768, 768);
    wtrans_kernel<<<dim3(24,12), tb, 0, stream>>>(Wv+(size_t)l*Cc*Cc, wqkvT+(size_t)l*2304*768+1536*768, 768, 768, 768);
    wtrans_kernel<<<dim3(24,12), tb, 0, stream>>>(Wp+(size_t)l*Cc*Cc, wpT+(size_t)l*768*768,             768, 768, 768);
    wtrans_kernel<<<dim3(96,12), tb, 0, stream>>>(Wf1+(size_t)l*Cc*4*Cc, wf1T+(size_t)l*3072*768,        768, 3072, 3072);
    wtrans_kernel<<<dim3(24,48), tb, 0, stream>>>(Wf2+(size_t)l*4*Cc*Cc, wf2T+(size_t)l*768*3072,        3072, 768, 768);
  }
  wtrans_kernel<<<dim3(VPAD/32,12), tb, 0, stream>>>(headW, headT, 768, Vv, VPAD);
  bconcat_kernel<<<(Ll*2304+255)/256, 256, 0, stream>>>(bq, bk, bv, bqkv);

  embed_kernel<<<NTOK*(Cc/4)/256, 256, 0, stream>>>(idx, tok, pos, x);

  for (int l=0;l<Ll;l++){
    ln_kernel<<<NTOK, 256, 0, stream>>>(x, ln1g+l*Cc, ln1b+l*Cc, h);
    mm_kernel<128,true,false,false,true,false><<<dim3(16,18,1), 256, 0, stream>>>(
        h, wqkvT+(size_t)l*2304*768, bqkv+l*2304, nullptr, qkv, 2304, 768, 768, 768, 2304);
    vtrans_kernel<<<dim3(32,2,Bsz*Hh), tb, 0, stream>>>(qkv, vT);
    flash_kernel<<<dim3(Tt/128, Bsz*Hh), 256, 0, stream>>>(qkv, vT, y);
    mm_kernel<64,true,true,false,false,false><<<dim3(16,12,1), 256, 0, stream>>>(
        y, wpT+(size_t)l*768*768, bp+l*Cc, x, x, 768, 768, 768, 768, 768);
    ln_kernel<<<NTOK, 256, 0, stream>>>(x, ln2g+l*Cc, ln2b+l*Cc, h);
    mm_kernel<128,true,false,true,true,false><<<dim3(16,24,1), 256, 0, stream>>>(
        h, wf1T+(size_t)l*3072*768, bf1+(size_t)l*4*Cc, nullptr, ff, 3072, 768, 768, 768, 3072);
    mm_kernel<64,true,true,false,false,false><<<dim3(16,12,1), 256, 0, stream>>>(
        ff, wf2T+(size_t)l*768*3072, bf2+l*Cc, x, x, 768, 3072, 3072, 3072, 768);
  }
  ln_kernel<<<NTOK, 256, 0, stream>>>(x, lnfg, lnfb, h);
  mm_kernel<128,false,false,false,false,true><<<dim3(16,VPAD/128,1), 256, 0, stream>>>(
      h, headT, nullptr, nullptr, outp, Vv, 768, 768, 768, Vv);
}

// Round 5
// 1329.813 us; speedup vs baseline: 1.4921x; 1.1637x over previous
//
#include <hip/hip_runtime.h>
#include <hip/hip_bf16.h>
#include <math.h>

// babyGPT-50m forward: B=2 T=1024 V=50257 C=768 H=12 L=6 D=64
#define Bsz 2
#define Tt 1024
#define Vv 50257
#define Cc 768
#define Hh 12
#define Ll 6
#define NTOK (Bsz*Tt)
#define VPAD 50304

typedef __attribute__((ext_vector_type(8))) short bf16x8;
typedef __attribute__((ext_vector_type(8))) unsigned short u16x8;
typedef __attribute__((ext_vector_type(4))) unsigned short u16x4;
typedef __attribute__((ext_vector_type(4))) float f32x4;
typedef unsigned short u16;

static __device__ __forceinline__ u16 f2bf(float f){
  unsigned u = __float_as_uint(f);
  u += 0x7FFF + ((u >> 16) & 1);   // RNE
  return (u16)(u >> 16);
}
static __device__ __forceinline__ float bf2f(u16 h){
  return __uint_as_float(((unsigned)h) << 16);
}

// async global->LDS, 16B per lane; LDS dest is wave-uniform base + lane*16
#define GL16(g,l) __builtin_amdgcn_global_load_lds( \
    (const __attribute__((address_space(1))) void*)(g), \
    (__attribute__((address_space(3))) void*)(l), 16, 0, 0)
#define WAITVM(n) asm volatile("s_waitcnt vmcnt(%0)" :: "n"(n) : "memory")

// ---------------- embedding: x = tok_emb[idx] + pos_emb (fp32) ----------------
__global__ void embed_kernel(const int* __restrict__ idx, const float* __restrict__ tok,
                             const float* __restrict__ pos, float* __restrict__ x){
  const int C4 = Cc/4;
  int i = blockIdx.x * 256 + threadIdx.x;
  if (i >= NTOK*C4) return;
  int tk = i / C4, c4 = i % C4;
  int row = idx[tk];
  int t = tk % Tt;
  float4 a = ((const float4*)tok)[(size_t)row*C4 + c4];
  float4 p = ((const float4*)pos)[(size_t)t*C4 + c4];
  float4 r; r.x=a.x+p.x; r.y=a.y+p.y; r.z=a.z+p.z; r.w=a.w+p.w;
  ((float4*)x)[i] = r;
}

// ---------------- layernorm: fp32 in -> bf16 out ----------------
__global__ void ln_kernel(const float* __restrict__ in, const float* __restrict__ g,
                          const float* __restrict__ bt, u16* __restrict__ out){
  int row = blockIdx.x, tid = threadIdx.x;
  const float* r = in + (size_t)row*Cc;
  float v0=r[tid], v1=r[tid+256], v2=r[tid+512];
  float s  = v0+v1+v2;
  float s2 = v0*v0+v1*v1+v2*v2;
  #pragma unroll
  for (int off=32; off; off>>=1){ s += __shfl_xor(s,off); s2 += __shfl_xor(s2,off); }
  __shared__ float red[8];
  int wid = tid >> 6;
  if ((tid & 63) == 0){ red[wid]=s; red[4+wid]=s2; }
  __syncthreads();
  float S  = red[0]+red[1]+red[2]+red[3];
  float S2 = red[4]+red[5]+red[6]+red[7];
  float mean = S * (1.0f/Cc);
  float var  = S2 * (1.0f/Cc) - mean*mean;
  float rstd = rsqrtf(var + 1e-5f);
  u16* o = out + (size_t)row*Cc;
  o[tid]     = f2bf((v0-mean)*rstd*g[tid]     + bt[tid]);
  o[tid+256] = f2bf((v1-mean)*rstd*g[tid+256] + bt[tid+256]);
  o[tid+512] = f2bf((v2-mean)*rstd*g[tid+512] + bt[tid+512]);
}

// ---- weight transpose+convert: fp32 [K][N] -> bf16 [Npad][K]; 64k x 32n tiles ----
// batched over layers via blockIdx.z
__global__ void wtrans_kernel(const float* __restrict__ in, u16* __restrict__ out,
                              int K, int N, int Npad, size_t lsi, size_t lso){
  __shared__ float t[64][33];
  const float* inp = in + (size_t)blockIdx.z*lsi;
  u16* op = out + (size_t)blockIdx.z*lso;
  int n0 = blockIdx.x*32, k0 = blockIdx.y*64;
  int tx = threadIdx.x, ty = threadIdx.y;   // block (32,8)
  #pragma unroll
  for (int i=0;i<8;i++){
    int k = k0+ty+i*8, n = n0+tx;
    t[ty+i*8][tx] = (n < N) ? inp[(size_t)k*N + n] : 0.f;
  }
  __syncthreads();
  #pragma unroll
  for (int i=0;i<2;i++){
    int nl = i*16 + ty*2 + (tx>>4);
    int kl = (tx&15)*4;
    int n = n0 + nl;
    if (n < Npad){
      u16x4 pk;
      pk[0] = f2bf(t[kl+0][nl]); pk[1] = f2bf(t[kl+1][nl]);
      pk[2] = f2bf(t[kl+2][nl]); pk[3] = f2bf(t[kl+3][nl]);
      *(u16x4*)&op[(size_t)n*K + k0 + kl] = pk;
    }
  }
}

// ---------------- v-part of qkv -> vT[b,h][d][t] (bf16) ----------------
__global__ void vtrans_kernel(const u16* __restrict__ qkv, u16* __restrict__ vT){
  __shared__ u16 s[32][33];
  int bh = blockIdx.z; int b = bh/Hh, h = bh - b*Hh;
  int t0 = blockIdx.x*32, d0 = blockIdx.y*32;
  int tx=threadIdx.x, ty=threadIdx.y;       // block (32,8)
  #pragma unroll
  for (int i=0;i<4;i++)
    s[ty+i*8][tx] = qkv[(size_t)(b*Tt + t0+ty+i*8)*2304 + 1536 + h*64 + d0 + tx];
  __syncthreads();
  #pragma unroll
  for (int i=0;i<4;i++)
    vT[((size_t)bh*64 + d0+ty+i*8)*Tt + t0 + tx] = s[tx][ty+i*8];
}

// ---------------- bias concat [L][2304] ----------------
__global__ void bconcat_kernel(const float* __restrict__ bq, const float* __restrict__ bk,
                               const float* __restrict__ bv, float* __restrict__ o){
  int i = blockIdx.x*256 + threadIdx.x;
  if (i >= Ll*2304) return;
  int l = i/2304, j = i - l*2304;
  o[i] = (j < 768) ? bq[l*768+j] : (j < 1536) ? bk[l*768+j-768] : bv[l*768+j-1536];
}

// ---------------- flash attention ----------------
// grid (T/128, B*H), 256 thr (4 waves). Q,K from qkv; V^T from vT; out y bf16 token-major.
__global__ __launch_bounds__(256) void flash_kernel(
    const u16* __restrict__ qkv, const u16* __restrict__ vT, u16* __restrict__ y){
  __shared__ u16 Ks[2][64*64];     // [s][k], 128B rows, XOR-swizzled
  __shared__ u16 Vs[2][64*64];     // [d][s], 128B rows, XOR-swizzled
  __shared__ u16 Ps[4][32*64];     // per-wave [q][s], 128B rows, XOR-swizzled
  int bx = blockIdx.x;
  int bh = blockIdx.y; int b = bh/Hh, h = bh - b*Hh;
  int q0 = bx*128;
  int tid = threadIdx.x, lane = tid&63, wid = tid>>6;
  const size_t tokbase = (size_t)b*Tt;
  int arow = lane&15, akof = (lane>>4)*8;
  bf16x8 qa[2][2];
  #pragma unroll
  for (int mi=0;mi<2;mi++)
    #pragma unroll
    for (int ks=0;ks<2;ks++)
      qa[mi][ks] = *(const bf16x8*)&qkv[(tokbase + q0 + wid*32 + mi*16 + arow)*2304
                                        + h*64 + ks*32 + akof];
  int srow = lane>>3;
  int sbyte = ((lane&7)*16) ^ (srow<<4);
  const u16* kbase = qkv + tokbase*2304 + 768 + h*64;
  const u16* vbase = vT + (size_t)bh*64*Tt;
  auto STAGEKV = [&](int t, int bb){
    int j0 = t*64;
    #pragma unroll
    for (int c=0;c<2;c++){
      int r = wid*16 + c*8 + srow;
      GL16(kbase + (size_t)(j0 + r)*2304 + (sbyte>>1), &Ks[bb][(wid*16 + c*8)*64]);
      GL16(vbase + (size_t)r*Tt + j0 + (sbyte>>1),     &Vs[bb][(wid*16 + c*8)*64]);
    }
  };
  float m_r[2][4], l_r[2][4];
  f32x4 o_acc[2][4] = {};
  #pragma unroll
  for (int mi=0;mi<2;mi++)
    #pragma unroll
    for (int jj=0;jj<4;jj++){ m_r[mi][jj] = -1e30f; l_r[mi][jj] = 0.f; }

  int njt = 2*bx + 2;
  STAGEKV(0, 0);
  asm volatile("s_waitcnt vmcnt(0)" ::: "memory");
  __builtin_amdgcn_s_barrier();
  for (int t=0; t<njt; t++){
    int cur = t&1;
    if (t+1 < njt) STAGEKV(t+1, cur^1);
    int j0 = t*64;
    f32x4 sacc[2][4] = {};
    #pragma unroll
    for (int ks=0;ks<2;ks++){
      bf16x8 kf[4];
      #pragma unroll
      for (int ni=0;ni<4;ni++){
        int s16 = ni*16 + (lane&15);
        int kb = (ks*64 + (lane>>4)*16) ^ ((s16&7)<<4);
        kf[ni] = *(const bf16x8*)((const char*)&Ks[cur][0] + s16*128 + kb);
      }
      #pragma unroll
      for (int mi=0;mi<2;mi++)
        #pragma unroll
        for (int ni=0;ni<4;ni++)
          sacc[mi][ni] = __builtin_amdgcn_mfma_f32_16x16x32_bf16(qa[mi][ks], kf[ni], sacc[mi][ni], 0,0,0);
    }
    float tmax[2][4];
    #pragma unroll
    for (int mi=0;mi<2;mi++)
      #pragma unroll
      for (int jj=0;jj<4;jj++) tmax[mi][jj] = -1e30f;
    #pragma unroll
    for (int mi=0;mi<2;mi++)
      #pragma unroll
      for (int ni=0;ni<4;ni++)
        #pragma unroll
        for (int jj=0;jj<4;jj++){
          float v = sacc[mi][ni][jj]*0.125f;
          int sg = j0 + ni*16 + (lane&15);
          int tg = q0 + wid*32 + mi*16 + (lane>>4)*4 + jj;
          v = (sg <= tg) ? v : -1e30f;
          sacc[mi][ni][jj] = v;
          tmax[mi][jj] = fmaxf(tmax[mi][jj], v);
        }
    #pragma unroll
    for (int mi=0;mi<2;mi++)
      #pragma unroll
      for (int jj=0;jj<4;jj++){
        float tm = tmax[mi][jj];
        tm = fmaxf(tm, __shfl_xor(tm,1)); tm = fmaxf(tm, __shfl_xor(tm,2));
        tm = fmaxf(tm, __shfl_xor(tm,4)); tm = fmaxf(tm, __shfl_xor(tm,8));
        float mn = fmaxf(m_r[mi][jj], tm);
        float al = __expf(m_r[mi][jj] - mn);
        m_r[mi][jj] = mn;
        l_r[mi][jj] *= al;
        tmax[mi][jj] = al;
      }
    float tsum[2][4] = {};
    #pragma unroll
    for (int mi=0;mi<2;mi++)
      #pragma unroll
      for (int ni=0;ni<4;ni++)
        #pragma unroll
        for (int jj=0;jj<4;jj++){
          float p = __expf(sacc[mi][ni][jj] - m_r[mi][jj]);
          tsum[mi][jj] += p;
          int pr = mi*16 + (lane>>4)*4 + jj;
          int pcb = (2*(ni*16 + (lane&15))) ^ ((pr&7)<<4);
          *(u16*)((char*)&Ps[wid][0] + pr*128 + pcb) = f2bf(p);
        }
    #pragma unroll
    for (int mi=0;mi<2;mi++)
      #pragma unroll
      for (int jj=0;jj<4;jj++){
        float ts = tsum[mi][jj];
        ts += __shfl_xor(ts,1); ts += __shfl_xor(ts,2);
        ts += __shfl_xor(ts,4); ts += __shfl_xor(ts,8);
        l_r[mi][jj] += ts;
        float al = tmax[mi][jj];
        #pragma unroll
        for (int ni2=0;ni2<4;ni2++) o_acc[mi][ni2][jj] *= al;
      }
    #pragma unroll
    for (int ks2=0;ks2<2;ks2++){
      bf16x8 pa[2], vf[4];
      #pragma unroll
      for (int mi=0;mi<2;mi++){
        int prr = mi*16 + (lane&15);
        int pb = (ks2*64 + (lane>>4)*16) ^ ((prr&7)<<4);
        pa[mi] = *(const bf16x8*)((const char*)&Ps[wid][0] + prr*128 + pb);
      }
      #pragma unroll
      for (int ni2=0;ni2<4;ni2++){
        int d16 = ni2*16 + (lane&15);
        int sb = (ks2*64 + (lane>>4)*16) ^ ((d16&7)<<4);
        vf[ni2] = *(const bf16x8*)((const char*)&Vs[cur][0] + d16*128 + sb);
      }
      #pragma unroll
      for (int mi=0;mi<2;mi++)
        #pragma unroll
        for (int ni2=0;ni2<4;ni2++)
          o_acc[mi][ni2] = __builtin_amdgcn_mfma_f32_16x16x32_bf16(pa[mi], vf[ni2], o_acc[mi][ni2], 0,0,0);
    }
    asm volatile("s_waitcnt vmcnt(0) lgkmcnt(0)" ::: "memory");
    __builtin_amdgcn_s_barrier();
  }
  #pragma unroll
  for (int mi=0;mi<2;mi++)
    #pragma unroll
    for (int jj=0;jj<4;jj++){
      float inv = 1.0f / l_r[mi][jj];
      int tok2 = q0 + wid*32 + mi*16 + (lane>>4)*4 + jj;
      size_t rb = (tokbase + tok2)*Cc + h*64;
      #pragma unroll
      for (int ni2=0;ni2<4;ni2++)
        y[rb + ni2*16 + (lane&15)] = f2bf(o_acc[mi][ni2][jj] * inv);
    }
}

// -------- MFMA GEMM: BMxBN tile, BK=32, 3-buffer counted-vmcnt pipeline (T4) --------
template<int BM, int BN, bool BIAS, bool RESID, bool GELU, bool OUTBF, bool ROWSCAN>
__global__ __launch_bounds__(256) void mm_kernel(
    const u16* __restrict__ A, const u16* __restrict__ Bm,
    const float* __restrict__ bias, const float* __restrict__ resid,
    void* __restrict__ out, int N, int K, int lda, int ldb, int ldc)
{
  constexpr int FM   = BM/32;
  constexpr int FN   = BN/32;
  constexpr int CPW  = FN*16;
  constexpr int ESTR = CPW + 4;
  constexpr int ABUF = BM*32;          // u16 elems per A buffer
  constexpr int BBUF = BN*32;
  constexpr int LOADS = (BM+BN)/64;    // GL16 per wave per stage
  constexpr int SMEM_STAGE = 3*(ABUF+BBUF)*2;
  constexpr int SMEM_EPI   = 4*16*ESTR*4;
  constexpr int SMEMB = SMEM_STAGE > SMEM_EPI ? SMEM_STAGE : SMEM_EPI;
  __shared__ __align__(16) char smem[SMEMB];
  u16* As = (u16*)smem;                // [3][ABUF]
  u16* Bs = As + 3*ABUF;               // [3][BBUF]

  int bx = blockIdx.x, by = blockIdx.y;
  {                                    // bijective XCD swizzle (m204)
    int gx = gridDim.x;
    int nwg = gx * gridDim.y;
    int flat = by*gx + bx;
    int qq = nwg >> 3, rr = nwg & 7;
    int xcd = flat & 7, lid = flat >> 3;
    int swz = (xcd < rr) ? xcd*(qq+1) + lid : rr*(qq+1) + (xcd-rr)*qq + lid;
    bx = swz % gx; by = swz / gx;
  }
  int m0 = bx*BM, n0 = by*BN;
  int tid = threadIdx.x, lane = tid & 63, wid = tid >> 6;
  int wr = wid >> 1, wc = wid & 1;
  int r0 = wr*(BM/2), c0 = wc*(BN/2);
  int lrow = lane & 15, koff = (lane >> 4)*8;
  int sr = lane >> 2, sk = (lane & 3)*8;
  const u16* Ap = A + (size_t)(m0 + wid*(BM/4) + sr)*lda + sk;
  const u16* Bp = Bm + (size_t)(n0 + wid*(BN/4) + sr)*ldb + sk;
  int nt = K/32;
  auto STAGE = [&](int t, int bb){
    int kk = t*32;
    u16* Al = As + bb*ABUF + wid*(ABUF/4);
    GL16(Ap + kk, Al);
    if constexpr (BM==128) GL16(Ap + kk + (size_t)16*lda, Al + 512);
    u16* Bl = Bs + bb*BBUF + wid*(BBUF/4);
    GL16(Bp + kk, Bl);
    if constexpr (BN==128) GL16(Bp + kk + (size_t)16*ldb, Bl + 512);
  };
  f32x4 acc[FM][FN] = {};
  STAGE(0, 0);
  if (nt > 1) STAGE(1, 1);
  WAITVM(LOADS);                       // tile 0 complete (tile 1 may be in flight)
  __builtin_amdgcn_s_barrier();
  for (int t = 0; t < nt; t++){
    int bb = t % 3;
    if (t+2 < nt) STAGE(t+2, (t+2)%3);
    const u16* Ab2 = As + bb*ABUF;
    const u16* Bb2 = Bs + bb*BBUF;
    bf16x8 af[FM], bfr[FN];
    #pragma unroll
    for (int m=0;m<FM;m++) af[m] = *(const bf16x8*)&Ab2[(r0 + m*16 + lrow)*32 + koff];
    #pragma unroll
    for (int n=0;n<FN;n++) bfr[n] = *(const bf16x8*)&Bb2[(c0 + n*16 + lrow)*32 + koff];
    #pragma unroll
    for (int m=0;m<FM;m++)
      #pragma unroll
      for (int n=0;n<FN;n++)
        acc[m][n] = __builtin_amdgcn_mfma_f32_16x16x32_bf16(af[m], bfr[n], acc[m][n], 0,0,0);
    // wait: tile t+1's loads done (only t+2's LOADS may remain in flight)
    if (t+2 < nt) WAITVM(LOADS); else WAITVM(0);
    __builtin_amdgcn_s_barrier();
  }

  // ---- epilogue: per-wave-private LDS transpose tile, coalesced stores ----
  float* ebuf = (float*)smem + wid*16*ESTR;
  int er = lane >> 2;
  int ec = (lane & 3) * (CPW/4);
  #pragma unroll
  for (int m=0;m<FM;m++){
    #pragma unroll
    for (int n=0;n<FN;n++)
      #pragma unroll
      for (int j=0;j<4;j++)
        ebuf[((lane>>4)*4+j)*ESTR + n*16 + (lane&15)] = acc[m][n][j];
    __builtin_amdgcn_s_waitcnt(0);     // lgkm drain for own-wave LDS RAW
    if constexpr (ROWSCAN){
      #pragma unroll
      for (int rr2=0; rr2<16; rr2++){
        int gr2 = m0 + r0 + m*16 + rr2;
        int gc2 = n0 + c0 + lane;
        float v = ebuf[rr2*ESTR + lane];
        if (gc2 < N) ((float*)out)[(size_t)gr2*ldc + gc2] = v;
      }
    } else {
      int grow = m0 + r0 + m*16 + er;
      int gcol = n0 + c0 + ec;
      size_t rbase = (size_t)grow*ldc;
      if constexpr (OUTBF){
        u16 tmp[CPW/4];
        #pragma unroll
        for (int q=0;q<FN;q++){
          float4 v = *(const float4*)&ebuf[er*ESTR + ec + q*4];
          float f0=v.x, f1=v.y, f2=v.z, f3=v.w;
          if (BIAS){
            float4 b4 = *(const float4*)&bias[gcol + q*4];
            f0+=b4.x; f1+=b4.y; f2+=b4.z; f3+=b4.w;
          }
          if (GELU){
            f0 = 0.5f*f0*(1.f+erff(f0*0.70710678118654752f));
            f1 = 0.5f*f1*(1.f+erff(f1*0.70710678118654752f));
            f2 = 0.5f*f2*(1.f+erff(f2*0.70710678118654752f));
            f3 = 0.5f*f3*(1.f+erff(f3*0.70710678118654752f));
          }
          tmp[q*4+0]=f2bf(f0); tmp[q*4+1]=f2bf(f1);
          tmp[q*4+2]=f2bf(f2); tmp[q*4+3]=f2bf(f3);
        }
        #pragma unroll
        for (int s2=0; s2<CPW/32; s2++)
          *(u16x8*)&((u16*)out)[rbase + gcol + s2*8] = *(const u16x8*)&tmp[s2*8];
      } else {
        #pragma unroll
        for (int q=0;q<FN;q++){
          float4 v = *(const float4*)&ebuf[er*ESTR + ec + q*4];
          float f0=v.x, f1=v.y, f2=v.z, f3=v.w;
          if (BIAS){
            float4 b4 = *(const float4*)&bias[gcol + q*4];
            f0+=b4.x; f1+=b4.y; f2+=b4.z; f3+=b4.w;
          }
          if (GELU){
            f0 = 0.5f*f0*(1.f+erff(f0*0.70710678118654752f));
            f1 = 0.5f*f1*(1.f+erff(f1*0.70710678118654752f));
            f2 = 0.5f*f2*(1.f+erff(f2*0.70710678118654752f));
            f3 = 0.5f*f3*(1.f+erff(f3*0.70710678118654752f));
          }
          if (RESID){
            float4 r4 = *(const float4*)&resid[rbase + gcol + q*4];
            f0+=r4.x; f1+=r4.y; f2+=r4.z; f3+=r4.w;
          }
          float4 o4; o4.x=f0; o4.y=f1; o4.z=f2; o4.w=f3;
          *(float4*)&((float*)out)[rbase + gcol + q*4] = o4;
        }
      }
    }
  }
}

// ---------------- orchestration ----------------
extern "C" void kernel_launch(void* const* d_in, const int* in_sizes, int n_in,
                              void* d_out, int out_size, void* d_ws, size_t ws_size,
                              hipStream_t stream){
  const int*   idx  = (const int*)d_in[0];
  const float* tok  = (const float*)d_in[1];
  const float* pos  = (const float*)d_in[2];
  const float* ln1g = (const float*)d_in[3];
  const float* ln1b = (const float*)d_in[4];
  const float* Wq   = (const float*)d_in[5];
  const float* bq   = (const float*)d_in[6];
  const float* Wk   = (const float*)d_in[7];
  const float* bk   = (const float*)d_in[8];
  const float* Wv   = (const float*)d_in[9];
  const float* bv   = (const float*)d_in[10];
  const float* Wp   = (const float*)d_in[11];
  const float* bp   = (const float*)d_in[12];
  const float* ln2g = (const float*)d_in[13];
  const float* ln2b = (const float*)d_in[14];
  const float* Wf1  = (const float*)d_in[15];
  const float* bf1  = (const float*)d_in[16];
  const float* Wf2  = (const float*)d_in[17];
  const float* bf2  = (const float*)d_in[18];
  const float* lnfg = (const float*)d_in[19];
  const float* lnfb = (const float*)d_in[20];
  const float* headW= (const float*)d_in[21];
  float* outp = (float*)d_out;

  char* w = (char*)d_ws;
  u16* wqkvT = (u16*)w;  w += (size_t)Ll*2304*768*2;
  u16* wpT   = (u16*)w;  w += (size_t)Ll*768*768*2;
  u16* wf1T  = (u16*)w;  w += (size_t)Ll*3072*768*2;
  u16* wf2T  = (u16*)w;  w += (size_t)Ll*768*3072*2;
  u16* headT = (u16*)w;  w += (size_t)VPAD*768*2;
  float* bqkv= (float*)w;w += (size_t)Ll*2304*4;
  float* x   = (float*)w;w += (size_t)NTOK*Cc*4;
  u16* h     = (u16*)w;  w += (size_t)NTOK*Cc*2;
  u16* qkv   = (u16*)w;  w += (size_t)NTOK*2304*2;
  u16* vT    = (u16*)w;  w += (size_t)Bsz*Hh*64*Tt*2;
  u16* y     = (u16*)w;  w += (size_t)NTOK*Cc*2;
  u16* ff    = (u16*)w;  w += (size_t)NTOK*4*Cc*2;

  dim3 tb(32,8);
  wtrans_kernel<<<dim3(24,12,Ll), tb, 0, stream>>>(Wq, wqkvT,          768, 768, 768, (size_t)Cc*Cc, (size_t)2304*768);
  wtrans_kernel<<<dim3(24,12,Ll), tb, 0, stream>>>(Wk, wqkvT+768*768,  768, 768, 768, (size_t)Cc*Cc, (size_t)2304*768);
  wtrans_kernel<<<dim3(24,12,Ll), tb, 0, stream>>>(Wv, wqkvT+1536*768, 768, 768, 768, (size_t)Cc*Cc, (size_t)2304*768);
  wtrans_kernel<<<dim3(24,12,Ll), tb, 0, stream>>>(Wp, wpT,            768, 768, 768, (size_t)Cc*Cc, (size_t)768*768);
  wtrans_kernel<<<dim3(96,12,Ll), tb, 0, stream>>>(Wf1, wf1T,          768, 3072, 3072, (size_t)Cc*4*Cc, (size_t)3072*768);
  wtrans_kernel<<<dim3(24,48,Ll), tb, 0, stream>>>(Wf2, wf2T,          3072, 768, 768, (size_t)4*Cc*Cc, (size_t)768*3072);
  wtrans_kernel<<<dim3(VPAD/32,12,1), tb, 0, stream>>>(headW, headT, 768, Vv, VPAD, 0, 0);
  bconcat_kernel<<<(Ll*2304+255)/256, 256, 0, stream>>>(bq, bk, bv, bqkv);

  embed_kernel<<<NTOK*(Cc/4)/256, 256, 0, stream>>>(idx, tok, pos, x);

  for (int l=0;l<Ll;l++){
    ln_kernel<<<NTOK, 256, 0, stream>>>(x, ln1g+l*Cc, ln1b+l*Cc, h);
    mm_kernel<64,128,true,false,false,true,false><<<dim3(32,18,1), 256, 0, stream>>>(
        h, wqkvT+(size_t)l*2304*768, bqkv+l*2304, nullptr, qkv, 2304, 768, 768, 768, 2304);
    vtrans_kernel<<<dim3(32,2,Bsz*Hh), tb, 0, stream>>>(qkv, vT);
    flash_kernel<<<dim3(Tt/128, Bsz*Hh), 256, 0, stream>>>(qkv, vT, y);
    mm_kernel<64,64,true,true,false,false,false><<<dim3(32,12,1), 256, 0, stream>>>(
        y, wpT+(size_t)l*768*768, bp+l*Cc, x, x, 768, 768, 768, 768, 768);
    ln_kernel<<<NTOK, 256, 0, stream>>>(x, ln2g+l*Cc, ln2b+l*Cc, h);
    mm_kernel<64,128,true,false,true,true,false><<<dim3(32,24,1), 256, 0, stream>>>(
        h, wf1T+(size_t)l*3072*768, bf1+(size_t)l*4*Cc, nullptr, ff, 3072, 768, 768, 768, 3072);
    mm_kernel<64,64,true,true,false,false,false><<<dim3(32,12,1), 256, 0, stream>>>(
        ff, wf2T+(size_t)l*768*3072, bf2+l*Cc, x, x, 768, 3072, 3072, 3072, 768);
  }
  ln_kernel<<<NTOK, 256, 0, stream>>>(x, lnfg, lnfb, h);
  mm_kernel<128,128,false,false,false,false,true><<<dim3(16,VPAD/128,1), 256, 0, stream>>>(
      h, headT, nullptr, nullptr, outp, Vv, 768, 768, 768, Vv);
}

// Round 6
// 1248.554 us; speedup vs baseline: 1.5892x; 1.0651x over previous
//
#include <hip/hip_runtime.h>
#include <hip/hip_bf16.h>
#include <math.h>

// babyGPT-50m forward: B=2 T=1024 V=50257 C=768 H=12 L=6 D=64
#define Bsz 2
#define Tt 1024
#define Vv 50257
#define Cc 768
#define Hh 12
#define Ll 6
#define NTOK (Bsz*Tt)
#define VPAD 50304

typedef __attribute__((ext_vector_type(8))) short bf16x8;
typedef __attribute__((ext_vector_type(8))) unsigned short u16x8;
typedef __attribute__((ext_vector_type(4))) unsigned short u16x4;
typedef __attribute__((ext_vector_type(4))) float f32x4;
typedef unsigned short u16;

static __device__ __forceinline__ u16 f2bf(float f){
  unsigned u = __float_as_uint(f);
  u += 0x7FFF + ((u >> 16) & 1);   // RNE
  return (u16)(u >> 16);
}
static __device__ __forceinline__ float bf2f(u16 h){
  return __uint_as_float(((unsigned)h) << 16);
}

// async global->LDS, 16B per lane; LDS dest is wave-uniform base + lane*16
#define GL16(g,l) __builtin_amdgcn_global_load_lds( \
    (const __attribute__((address_space(1))) void*)(g), \
    (__attribute__((address_space(3))) void*)(l), 16, 0, 0)
#define WAITVM(n) asm volatile("s_waitcnt vmcnt(%0)" :: "n"(n) : "memory")

// ---------------- embedding: x = tok_emb[idx] + pos_emb (fp32) ----------------
__global__ void embed_kernel(const int* __restrict__ idx, const float* __restrict__ tok,
                             const float* __restrict__ pos, float* __restrict__ x){
  const int C4 = Cc/4;
  int i = blockIdx.x * 256 + threadIdx.x;
  if (i >= NTOK*C4) return;
  int tk = i / C4, c4 = i % C4;
  int row = idx[tk];
  int t = tk % Tt;
  float4 a = ((const float4*)tok)[(size_t)row*C4 + c4];
  float4 p = ((const float4*)pos)[(size_t)t*C4 + c4];
  float4 r; r.x=a.x+p.x; r.y=a.y+p.y; r.z=a.z+p.z; r.w=a.w+p.w;
  ((float4*)x)[i] = r;
}

// ---------------- layernorm: fp32 in -> bf16 out ----------------
__global__ void ln_kernel(const float* __restrict__ in, const float* __restrict__ g,
                          const float* __restrict__ bt, u16* __restrict__ out){
  int row = blockIdx.x, tid = threadIdx.x;
  const float* r = in + (size_t)row*Cc;
  float v0=r[tid], v1=r[tid+256], v2=r[tid+512];
  float s  = v0+v1+v2;
  float s2 = v0*v0+v1*v1+v2*v2;
  #pragma unroll
  for (int off=32; off; off>>=1){ s += __shfl_xor(s,off); s2 += __shfl_xor(s2,off); }
  __shared__ float red[8];
  int wid = tid >> 6;
  if ((tid & 63) == 0){ red[wid]=s; red[4+wid]=s2; }
  __syncthreads();
  float S  = red[0]+red[1]+red[2]+red[3];
  float S2 = red[4]+red[5]+red[6]+red[7];
  float mean = S * (1.0f/Cc);
  float var  = S2 * (1.0f/Cc) - mean*mean;
  float rstd = rsqrtf(var + 1e-5f);
  u16* o = out + (size_t)row*Cc;
  o[tid]     = f2bf((v0-mean)*rstd*g[tid]     + bt[tid]);
  o[tid+256] = f2bf((v1-mean)*rstd*g[tid+256] + bt[tid+256]);
  o[tid+512] = f2bf((v2-mean)*rstd*g[tid+512] + bt[tid+512]);
}

// ---- weight transpose+convert: fp32 [K][N] -> bf16 [Npad][K]; 64k x 32n tiles ----
__global__ void wtrans_kernel(const float* __restrict__ in, u16* __restrict__ out,
                              int K, int N, int Npad, size_t lsi, size_t lso){
  __shared__ float t[64][33];
  const float* inp = in + (size_t)blockIdx.z*lsi;
  u16* op = out + (size_t)blockIdx.z*lso;
  int n0 = blockIdx.x*32, k0 = blockIdx.y*64;
  int tx = threadIdx.x, ty = threadIdx.y;   // block (32,8)
  #pragma unroll
  for (int i=0;i<8;i++){
    int k = k0+ty+i*8, n = n0+tx;
    t[ty+i*8][tx] = (n < N) ? inp[(size_t)k*N + n] : 0.f;
  }
  __syncthreads();
  #pragma unroll
  for (int i=0;i<2;i++){
    int nl = i*16 + ty*2 + (tx>>4);
    int kl = (tx&15)*4;
    int n = n0 + nl;
    if (n < Npad){
      u16x4 pk;
      pk[0] = f2bf(t[kl+0][nl]); pk[1] = f2bf(t[kl+1][nl]);
      pk[2] = f2bf(t[kl+2][nl]); pk[3] = f2bf(t[kl+3][nl]);
      *(u16x4*)&op[(size_t)n*K + k0 + kl] = pk;
    }
  }
}

// ---------------- v-part of qkv -> vT[b,h][d][t] (bf16) ----------------
__global__ void vtrans_kernel(const u16* __restrict__ qkv, u16* __restrict__ vT){
  __shared__ u16 s[32][33];
  int bh = blockIdx.z; int b = bh/Hh, h = bh - b*Hh;
  int t0 = blockIdx.x*32, d0 = blockIdx.y*32;
  int tx=threadIdx.x, ty=threadIdx.y;       // block (32,8)
  #pragma unroll
  for (int i=0;i<4;i++)
    s[ty+i*8][tx] = qkv[(size_t)(b*Tt + t0+ty+i*8)*2304 + 1536 + h*64 + d0 + tx];
  __syncthreads();
  #pragma unroll
  for (int i=0;i<4;i++)
    vT[((size_t)bh*64 + d0+ty+i*8)*Tt + t0 + tx] = s[tx][ty+i*8];
}

// ---------------- bias concat [L][2304] ----------------
__global__ void bconcat_kernel(const float* __restrict__ bq, const float* __restrict__ bk,
                               const float* __restrict__ bv, float* __restrict__ o){
  int i = blockIdx.x*256 + threadIdx.x;
  if (i >= Ll*2304) return;
  int l = i/2304, j = i - l*2304;
  o[i] = (j < 768) ? bq[l*768+j] : (j < 1536) ? bk[l*768+j-768] : bv[l*768+j-1536];
}

// ---------------- flash attention, QB=64 ----------------
// grid (T/64, B*H), 256 thr (4 waves, 16 q-rows each). Q,K from qkv; V^T from vT.
__global__ __launch_bounds__(256) void flash_kernel(
    const u16* __restrict__ qkv, const u16* __restrict__ vT, u16* __restrict__ y){
  __shared__ u16 Ks[2][64*64];     // [s][k], 128B rows, XOR-swizzled
  __shared__ u16 Vs[2][64*64];     // [d][s], 128B rows, XOR-swizzled
  __shared__ u16 Ps[4][16*64];     // per-wave [q][s], 128B rows, XOR-swizzled
  int bx = blockIdx.x;
  int bh = blockIdx.y; int b = bh/Hh, h = bh - b*Hh;
  int q0 = bx*64;
  int tid = threadIdx.x, lane = tid&63, wid = tid>>6;
  const size_t tokbase = (size_t)b*Tt;
  int arow = lane&15, akof = (lane>>4)*8;
  bf16x8 qa[2];
  #pragma unroll
  for (int ks=0;ks<2;ks++)
    qa[ks] = *(const bf16x8*)&qkv[(tokbase + q0 + wid*16 + arow)*2304
                                  + h*64 + ks*32 + akof];
  int srow = lane>>3;
  int sbyte = ((lane&7)*16) ^ (srow<<4);
  const u16* kbase = qkv + tokbase*2304 + 768 + h*64;
  const u16* vbase = vT + (size_t)bh*64*Tt;
  auto STAGEKV = [&](int t, int bb){
    int j0 = t*64;
    #pragma unroll
    for (int c=0;c<2;c++){
      int r = wid*16 + c*8 + srow;
      GL16(kbase + (size_t)(j0 + r)*2304 + (sbyte>>1), &Ks[bb][(wid*16 + c*8)*64]);
      GL16(vbase + (size_t)r*Tt + j0 + (sbyte>>1),     &Vs[bb][(wid*16 + c*8)*64]);
    }
  };
  float m_r[4], l_r[4];
  f32x4 o_acc[4] = {};
  #pragma unroll
  for (int jj=0;jj<4;jj++){ m_r[jj] = -1e30f; l_r[jj] = 0.f; }

  int njt = bx + 1;
  STAGEKV(0, 0);
  asm volatile("s_waitcnt vmcnt(0)" ::: "memory");
  __builtin_amdgcn_s_barrier();
  for (int t=0; t<njt; t++){
    int cur = t&1;
    if (t+1 < njt) STAGEKV(t+1, cur^1);
    int j0 = t*64;
    // ---- S = Q K^T ----
    f32x4 sacc[4] = {};
    #pragma unroll
    for (int ks=0;ks<2;ks++){
      bf16x8 kf[4];
      #pragma unroll
      for (int ni=0;ni<4;ni++){
        int s16 = ni*16 + (lane&15);
        int kb = (ks*64 + (lane>>4)*16) ^ ((s16&7)<<4);
        kf[ni] = *(const bf16x8*)((const char*)&Ks[cur][0] + s16*128 + kb);
      }
      #pragma unroll
      for (int ni=0;ni<4;ni++)
        sacc[ni] = __builtin_amdgcn_mfma_f32_16x16x32_bf16(qa[ks], kf[ni], sacc[ni], 0,0,0);
    }
    // ---- scale + causal mask + online softmax ----
    float tmax[4];
    #pragma unroll
    for (int jj=0;jj<4;jj++) tmax[jj] = -1e30f;
    #pragma unroll
    for (int ni=0;ni<4;ni++)
      #pragma unroll
      for (int jj=0;jj<4;jj++){
        float v = sacc[ni][jj]*0.125f;
        int sg = j0 + ni*16 + (lane&15);
        int tg = q0 + wid*16 + (lane>>4)*4 + jj;
        v = (sg <= tg) ? v : -1e30f;
        sacc[ni][jj] = v;
        tmax[jj] = fmaxf(tmax[jj], v);
      }
    #pragma unroll
    for (int jj=0;jj<4;jj++){
      float tm = tmax[jj];
      tm = fmaxf(tm, __shfl_xor(tm,1)); tm = fmaxf(tm, __shfl_xor(tm,2));
      tm = fmaxf(tm, __shfl_xor(tm,4)); tm = fmaxf(tm, __shfl_xor(tm,8));
      float mn = fmaxf(m_r[jj], tm);
      float al = __expf(m_r[jj] - mn);
      m_r[jj] = mn;
      l_r[jj] *= al;
      tmax[jj] = al;           // reuse as alpha
    }
    float tsum[4] = {};
    #pragma unroll
    for (int ni=0;ni<4;ni++)
      #pragma unroll
      for (int jj=0;jj<4;jj++){
        float p = __expf(sacc[ni][jj] - m_r[jj]);
        tsum[jj] += p;
        int pr = (lane>>4)*4 + jj;
        int pcb = (2*(ni*16 + (lane&15))) ^ ((pr&7)<<4);
        *(u16*)((char*)&Ps[wid][0] + pr*128 + pcb) = f2bf(p);
      }
    #pragma unroll
    for (int jj=0;jj<4;jj++){
      float ts = tsum[jj];
      ts += __shfl_xor(ts,1); ts += __shfl_xor(ts,2);
      ts += __shfl_xor(ts,4); ts += __shfl_xor(ts,8);
      l_r[jj] += ts;
      float al = tmax[jj];
      #pragma unroll
      for (int ni2=0;ni2<4;ni2++) o_acc[ni2][jj] *= al;
    }
    // ---- O += P V ----
    #pragma unroll
    for (int ks2=0;ks2<2;ks2++){
      bf16x8 pa, vf[4];
      int prr = lane&15;
      int pb = (ks2*64 + (lane>>4)*16) ^ ((prr&7)<<4);
      pa = *(const bf16x8*)((const char*)&Ps[wid][0] + prr*128 + pb);
      #pragma unroll
      for (int ni2=0;ni2<4;ni2++){
        int d16 = ni2*16 + (lane&15);
        int sb = (ks2*64 + (lane>>4)*16) ^ ((d16&7)<<4);
        vf[ni2] = *(const bf16x8*)((const char*)&Vs[cur][0] + d16*128 + sb);
      }
      #pragma unroll
      for (int ni2=0;ni2<4;ni2++)
        o_acc[ni2] = __builtin_amdgcn_mfma_f32_16x16x32_bf16(pa, vf[ni2], o_acc[ni2], 0,0,0);
    }
    asm volatile("s_waitcnt vmcnt(0) lgkmcnt(0)" ::: "memory");
    __builtin_amdgcn_s_barrier();
  }
  // ---- normalize + store ----
  #pragma unroll
  for (int jj=0;jj<4;jj++){
    float inv = 1.0f / l_r[jj];
    int tok2 = q0 + wid*16 + (lane>>4)*4 + jj;
    size_t rb = (tokbase + tok2)*Cc + h*64;
    #pragma unroll
    for (int ni2=0;ni2<4;ni2++)
      y[rb + ni2*16 + (lane&15)] = f2bf(o_acc[ni2][jj] * inv);
  }
}

// -------- MFMA GEMM: BMxBN tile, BK=32, NBUF-deep pipeline --------
// NBUF=2: stage(t+1)->compute(t)->drain->barrier (max co-residency, head)
// NBUF=3: stage(t+2)->compute(t)->vmcnt(LOADS)->barrier (counted, layer GEMMs)
template<int NBUF, int BM, int BN, bool BIAS, bool RESID, bool GELU, bool OUTBF, bool ROWSCAN>
__global__ __launch_bounds__(256) void mm_kernel(
    const u16* __restrict__ A, const u16* __restrict__ Bm,
    const float* __restrict__ bias, const float* __restrict__ resid,
    void* __restrict__ out, int N, int K, int lda, int ldb, int ldc)
{
  constexpr int FM   = BM/32;
  constexpr int FN   = BN/32;
  constexpr int CPW  = FN*16;
  constexpr int ESTR = CPW + 4;
  constexpr int ABUF = BM*32;
  constexpr int BBUF = BN*32;
  constexpr int LOADS = (BM+BN)/64;
  constexpr int SMEM_STAGE = NBUF*(ABUF+BBUF)*2;
  constexpr int SMEM_EPI   = 4*16*ESTR*4;
  constexpr int SMEMB = SMEM_STAGE > SMEM_EPI ? SMEM_STAGE : SMEM_EPI;
  __shared__ __align__(16) char smem[SMEMB];
  u16* As = (u16*)smem;
  u16* Bs = As + NBUF*ABUF;

  int bx = blockIdx.x, by = blockIdx.y;
  {                                    // bijective XCD swizzle (m204)
    int gx = gridDim.x;
    int nwg = gx * gridDim.y;
    int flat = by*gx + bx;
    int qq = nwg >> 3, rr = nwg & 7;
    int xcd = flat & 7, lid = flat >> 3;
    int swz = (xcd < rr) ? xcd*(qq+1) + lid : rr*(qq+1) + (xcd-rr)*qq + lid;
    bx = swz % gx; by = swz / gx;
  }
  int m0 = bx*BM, n0 = by*BN;
  int tid = threadIdx.x, lane = tid & 63, wid = tid >> 6;
  int wr = wid >> 1, wc = wid & 1;
  int r0 = wr*(BM/2), c0 = wc*(BN/2);
  int lrow = lane & 15, koff = (lane >> 4)*8;
  int sr = lane >> 2, sk = (lane & 3)*8;
  const u16* Ap = A + (size_t)(m0 + wid*(BM/4) + sr)*lda + sk;
  const u16* Bp = Bm + (size_t)(n0 + wid*(BN/4) + sr)*ldb + sk;
  int nt = K/32;
  auto STAGE = [&](int t, int bb){
    int kk = t*32;
    u16* Al = As + bb*ABUF + wid*(ABUF/4);
    GL16(Ap + kk, Al);
    if constexpr (BM==128) GL16(Ap + kk + (size_t)16*lda, Al + 512);
    u16* Bl = Bs + bb*BBUF + wid*(BBUF/4);
    GL16(Bp + kk, Bl);
    if constexpr (BN==128) GL16(Bp + kk + (size_t)16*ldb, Bl + 512);
  };
  f32x4 acc[FM][FN] = {};
  if constexpr (NBUF==2){
    STAGE(0, 0);
    WAITVM(0);
    __builtin_amdgcn_s_barrier();
  } else {
    STAGE(0, 0);
    if (nt > 1) STAGE(1, 1);
    WAITVM(LOADS);
    __builtin_amdgcn_s_barrier();
  }
  for (int t = 0; t < nt; t++){
    int bb = (NBUF==2) ? (t & 1) : (t % 3);
    if constexpr (NBUF==2){
      if (t+1 < nt) STAGE(t+1, (t+1)&1);
    } else {
      if (t+2 < nt) STAGE(t+2, (t+2)%3);
    }
    const u16* Ab2 = As + bb*ABUF;
    const u16* Bb2 = Bs + bb*BBUF;
    bf16x8 af[FM], bfr[FN];
    #pragma unroll
    for (int m=0;m<FM;m++) af[m] = *(const bf16x8*)&Ab2[(r0 + m*16 + lrow)*32 + koff];
    #pragma unroll
    for (int n=0;n<FN;n++) bfr[n] = *(const bf16x8*)&Bb2[(c0 + n*16 + lrow)*32 + koff];
    #pragma unroll
    for (int m=0;m<FM;m++)
      #pragma unroll
      for (int n=0;n<FN;n++)
        acc[m][n] = __builtin_amdgcn_mfma_f32_16x16x32_bf16(af[m], bfr[n], acc[m][n], 0,0,0);
    if constexpr (NBUF==2){
      asm volatile("s_waitcnt vmcnt(0) lgkmcnt(0)" ::: "memory");
    } else {
      if (t+2 < nt) WAITVM(LOADS); else WAITVM(0);
    }
    __builtin_amdgcn_s_barrier();
  }

  // ---- epilogue: per-wave-private LDS transpose tile, coalesced stores ----
  float* ebuf = (float*)smem + wid*16*ESTR;
  int er = lane >> 2;
  int ec = (lane & 3) * (CPW/4);
  #pragma unroll
  for (int m=0;m<FM;m++){
    #pragma unroll
    for (int n=0;n<FN;n++)
      #pragma unroll
      for (int j=0;j<4;j++)
        ebuf[((lane>>4)*4+j)*ESTR + n*16 + (lane&15)] = acc[m][n][j];
    __builtin_amdgcn_s_waitcnt(0);     // lgkm drain for own-wave LDS RAW
    if constexpr (ROWSCAN){
      // fp32 out, arbitrary ldc; logits never re-read -> nontemporal stores
      #pragma unroll
      for (int rr2=0; rr2<16; rr2++){
        int gr2 = m0 + r0 + m*16 + rr2;
        int gc2 = n0 + c0 + lane;
        float v = ebuf[rr2*ESTR + lane];
        if (gc2 < N)
          __builtin_nontemporal_store(v, &((float*)out)[(size_t)gr2*ldc + gc2]);
      }
    } else {
      int grow = m0 + r0 + m*16 + er;
      int gcol = n0 + c0 + ec;
      size_t rbase = (size_t)grow*ldc;
      if constexpr (OUTBF){
        u16 tmp[CPW/4];
        #pragma unroll
        for (int q=0;q<FN;q++){
          float4 v = *(const float4*)&ebuf[er*ESTR + ec + q*4];
          float f0=v.x, f1=v.y, f2=v.z, f3=v.w;
          if (BIAS){
            float4 b4 = *(const float4*)&bias[gcol + q*4];
            f0+=b4.x; f1+=b4.y; f2+=b4.z; f3+=b4.w;
          }
          if (GELU){
            f0 = 0.5f*f0*(1.f+erff(f0*0.70710678118654752f));
            f1 = 0.5f*f1*(1.f+erff(f1*0.70710678118654752f));
            f2 = 0.5f*f2*(1.f+erff(f2*0.70710678118654752f));
            f3 = 0.5f*f3*(1.f+erff(f3*0.70710678118654752f));
          }
          tmp[q*4+0]=f2bf(f0); tmp[q*4+1]=f2bf(f1);
          tmp[q*4+2]=f2bf(f2); tmp[q*4+3]=f2bf(f3);
        }
        #pragma unroll
        for (int s2=0; s2<CPW/32; s2++)
          *(u16x8*)&((u16*)out)[rbase + gcol + s2*8] = *(const u16x8*)&tmp[s2*8];
      } else {
        #pragma unroll
        for (int q=0;q<FN;q++){
          float4 v = *(const float4*)&ebuf[er*ESTR + ec + q*4];
          float f0=v.x, f1=v.y, f2=v.z, f3=v.w;
          if (BIAS){
            float4 b4 = *(const float4*)&bias[gcol + q*4];
            f0+=b4.x; f1+=b4.y; f2+=b4.z; f3+=b4.w;
          }
          if (GELU){
            f0 = 0.5f*f0*(1.f+erff(f0*0.70710678118654752f));
            f1 = 0.5f*f1*(1.f+erff(f1*0.70710678118654752f));
            f2 = 0.5f*f2*(1.f+erff(f2*0.70710678118654752f));
            f3 = 0.5f*f3*(1.f+erff(f3*0.70710678118654752f));
          }
          if (RESID){
            float4 r4 = *(const float4*)&resid[rbase + gcol + q*4];
            f0+=r4.x; f1+=r4.y; f2+=r4.z; f3+=r4.w;
          }
          float4 o4; o4.x=f0; o4.y=f1; o4.z=f2; o4.w=f3;
          *(float4*)&((float*)out)[rbase + gcol + q*4] = o4;
        }
      }
    }
  }
}

// ---------------- orchestration ----------------
extern "C" void kernel_launch(void* const* d_in, const int* in_sizes, int n_in,
                              void* d_out, int out_size, void* d_ws, size_t ws_size,
                              hipStream_t stream){
  const int*   idx  = (const int*)d_in[0];
  const float* tok  = (const float*)d_in[1];
  const float* pos  = (const float*)d_in[2];
  const float* ln1g = (const float*)d_in[3];
  const float* ln1b = (const float*)d_in[4];
  const float* Wq   = (const float*)d_in[5];
  const float* bq   = (const float*)d_in[6];
  const float* Wk   = (const float*)d_in[7];
  const float* bk   = (const float*)d_in[8];
  const float* Wv   = (const float*)d_in[9];
  const float* bv   = (const float*)d_in[10];
  const float* Wp   = (const float*)d_in[11];
  const float* bp   = (const float*)d_in[12];
  const float* ln2g = (const float*)d_in[13];
  const float* ln2b = (const float*)d_in[14];
  const float* Wf1  = (const float*)d_in[15];
  const float* bf1  = (const float*)d_in[16];
  const float* Wf2  = (const float*)d_in[17];
  const float* bf2  = (const float*)d_in[18];
  const float* lnfg = (const float*)d_in[19];
  const float* lnfb = (const float*)d_in[20];
  const float* headW= (const float*)d_in[21];
  float* outp = (float*)d_out;

  char* w = (char*)d_ws;
  u16* wqkvT = (u16*)w;  w += (size_t)Ll*2304*768*2;
  u16* wpT   = (u16*)w;  w += (size_t)Ll*768*768*2;
  u16* wf1T  = (u16*)w;  w += (size_t)Ll*3072*768*2;
  u16* wf2T  = (u16*)w;  w += (size_t)Ll*768*3072*2;
  u16* headT = (u16*)w;  w += (size_t)VPAD*768*2;
  float* bqkv= (float*)w;w += (size_t)Ll*2304*4;
  float* x   = (float*)w;w += (size_t)NTOK*Cc*4;
  u16* h     = (u16*)w;  w += (size_t)NTOK*Cc*2;
  u16* qkv   = (u16*)w;  w += (size_t)NTOK*2304*2;
  u16* vT    = (u16*)w;  w += (size_t)Bsz*Hh*64*Tt*2;
  u16* y     = (u16*)w;  w += (size_t)NTOK*Cc*2;
  u16* ff    = (u16*)w;  w += (size_t)NTOK*4*Cc*2;

  dim3 tb(32,8);
  wtrans_kernel<<<dim3(24,12,Ll), tb, 0, stream>>>(Wq, wqkvT,          768, 768, 768, (size_t)Cc*Cc, (size_t)2304*768);
  wtrans_kernel<<<dim3(24,12,Ll), tb, 0, stream>>>(Wk, wqkvT+768*768,  768, 768, 768, (size_t)Cc*Cc, (size_t)2304*768);
  wtrans_kernel<<<dim3(24,12,Ll), tb, 0, stream>>>(Wv, wqkvT+1536*768, 768, 768, 768, (size_t)Cc*Cc, (size_t)2304*768);
  wtrans_kernel<<<dim3(24,12,Ll), tb, 0, stream>>>(Wp, wpT,            768, 768, 768, (size_t)Cc*Cc, (size_t)768*768);
  wtrans_kernel<<<dim3(96,12,Ll), tb, 0, stream>>>(Wf1, wf1T,          768, 3072, 3072, (size_t)Cc*4*Cc, (size_t)3072*768);
  wtrans_kernel<<<dim3(24,48,Ll), tb, 0, stream>>>(Wf2, wf2T,          3072, 768, 768, (size_t)4*Cc*Cc, (size_t)768*3072);
  wtrans_kernel<<<dim3(VPAD/32,12,1), tb, 0, stream>>>(headW, headT, 768, Vv, VPAD, 0, 0);
  bconcat_kernel<<<(Ll*2304+255)/256, 256, 0, stream>>>(bq, bk, bv, bqkv);

  embed_kernel<<<NTOK*(Cc/4)/256, 256, 0, stream>>>(idx, tok, pos, x);

  for (int l=0;l<Ll;l++){
    ln_kernel<<<NTOK, 256, 0, stream>>>(x, ln1g+l*Cc, ln1b+l*Cc, h);
    mm_kernel<3,64,128,true,false,false,true,false><<<dim3(32,18,1), 256, 0, stream>>>(
        h, wqkvT+(size_t)l*2304*768, bqkv+l*2304, nullptr, qkv, 2304, 768, 768, 768, 2304);
    vtrans_kernel<<<dim3(32,2,Bsz*Hh), tb, 0, stream>>>(qkv, vT);
    flash_kernel<<<dim3(Tt/64, Bsz*Hh), 256, 0, stream>>>(qkv, vT, y);
    mm_kernel<3,64,64,true,true,false,false,false><<<dim3(32,12,1), 256, 0, stream>>>(
        y, wpT+(size_t)l*768*768, bp+l*Cc, x, x, 768, 768, 768, 768, 768);
    ln_kernel<<<NTOK, 256, 0, stream>>>(x, ln2g+l*Cc, ln2b+l*Cc, h);
    mm_kernel<3,64,128,true,false,true,true,false><<<dim3(32,24,1), 256, 0, stream>>>(
        h, wf1T+(size_t)l*3072*768, bf1+(size_t)l*4*Cc, nullptr, ff, 3072, 768, 768, 768, 3072);
    mm_kernel<3,64,64,true,true,false,false,false><<<dim3(32,12,1), 256, 0, stream>>>(
        ff, wf2T+(size_t)l*768*3072, bf2+l*Cc, x, x, 768, 3072, 3072, 3072, 768);
  }
  ln_kernel<<<NTOK, 256, 0, stream>>>(x, lnfg, lnfb, h);
  mm_kernel<2,128,128,false,false,false,false,true><<<dim3(16,VPAD/128,1), 256, 0, stream>>>(
      h, headT, nullptr, nullptr, outp, Vv, 768, 768, 768, Vv);
}

// Round 7
// 1147.962 us; speedup vs baseline: 1.7285x; 1.0876x over previous
//
#include <hip/hip_runtime.h>
#include <hip/hip_bf16.h>
#include <math.h>

// babyGPT-50m forward: B=2 T=1024 V=50257 C=768 H=12 L=6 D=64
#define Bsz 2
#define Tt 1024
#define Vv 50257
#define Cc 768
#define Hh 12
#define Ll 6
#define NTOK (Bsz*Tt)
#define VPAD 50304

typedef __attribute__((ext_vector_type(8))) short bf16x8;
typedef __attribute__((ext_vector_type(8))) unsigned short u16x8;
typedef __attribute__((ext_vector_type(4))) unsigned short u16x4;
typedef __attribute__((ext_vector_type(4))) float f32x4;
typedef unsigned short u16;

static __device__ __forceinline__ u16 f2bf(float f){
  unsigned u = __float_as_uint(f);
  u += 0x7FFF + ((u >> 16) & 1);   // RNE
  return (u16)(u >> 16);
}
static __device__ __forceinline__ float bf2f(u16 h){
  return __uint_as_float(((unsigned)h) << 16);
}

// async global->LDS, 16B per lane; LDS dest is wave-uniform base + lane*16
#define GL16(g,l) __builtin_amdgcn_global_load_lds( \
    (const __attribute__((address_space(1))) void*)(g), \
    (__attribute__((address_space(3))) void*)(l), 16, 0, 0)
#define WAITVM(n) asm volatile("s_waitcnt vmcnt(%0)" :: "n"(n) : "memory")

// ---------------- embedding: x = tok_emb[idx] + pos_emb (fp32) ----------------
__global__ void embed_kernel(const int* __restrict__ idx, const float* __restrict__ tok,
                             const float* __restrict__ pos, float* __restrict__ x){
  const int C4 = Cc/4;
  int i = blockIdx.x * 256 + threadIdx.x;
  if (i >= NTOK*C4) return;
  int tk = i / C4, c4 = i % C4;
  int row = idx[tk];
  int t = tk % Tt;
  float4 a = ((const float4*)tok)[(size_t)row*C4 + c4];
  float4 p = ((const float4*)pos)[(size_t)t*C4 + c4];
  float4 r; r.x=a.x+p.x; r.y=a.y+p.y; r.z=a.z+p.z; r.w=a.w+p.w;
  ((float4*)x)[i] = r;
}

// ---------------- layernorm: fp32 in -> bf16 out ----------------
__global__ void ln_kernel(const float* __restrict__ in, const float* __restrict__ g,
                          const float* __restrict__ bt, u16* __restrict__ out){
  int row = blockIdx.x, tid = threadIdx.x;
  const float* r = in + (size_t)row*Cc;
  float v0=r[tid], v1=r[tid+256], v2=r[tid+512];
  float s  = v0+v1+v2;
  float s2 = v0*v0+v1*v1+v2*v2;
  #pragma unroll
  for (int off=32; off; off>>=1){ s += __shfl_xor(s,off); s2 += __shfl_xor(s2,off); }
  __shared__ float red[8];
  int wid = tid >> 6;
  if ((tid & 63) == 0){ red[wid]=s; red[4+wid]=s2; }
  __syncthreads();
  float S  = red[0]+red[1]+red[2]+red[3];
  float S2 = red[4]+red[5]+red[6]+red[7];
  float mean = S * (1.0f/Cc);
  float var  = S2 * (1.0f/Cc) - mean*mean;
  float rstd = rsqrtf(var + 1e-5f);
  u16* o = out + (size_t)row*Cc;
  o[tid]     = f2bf((v0-mean)*rstd*g[tid]     + bt[tid]);
  o[tid+256] = f2bf((v1-mean)*rstd*g[tid+256] + bt[tid+256]);
  o[tid+512] = f2bf((v2-mean)*rstd*g[tid+512] + bt[tid+512]);
}

// ---- weight transpose+convert: fp32 [K][N] -> bf16 [Npad][K]; 64k x 32n tiles ----
__global__ void wtrans_kernel(const float* __restrict__ in, u16* __restrict__ out,
                              int K, int N, int Npad, size_t lsi, size_t lso){
  __shared__ float t[64][33];
  const float* inp = in + (size_t)blockIdx.z*lsi;
  u16* op = out + (size_t)blockIdx.z*lso;
  int n0 = blockIdx.x*32, k0 = blockIdx.y*64;
  int tx = threadIdx.x, ty = threadIdx.y;   // block (32,8)
  #pragma unroll
  for (int i=0;i<8;i++){
    int k = k0+ty+i*8, n = n0+tx;
    t[ty+i*8][tx] = (n < N) ? inp[(size_t)k*N + n] : 0.f;
  }
  __syncthreads();
  #pragma unroll
  for (int i=0;i<2;i++){
    int nl = i*16 + ty*2 + (tx>>4);
    int kl = (tx&15)*4;
    int n = n0 + nl;
    if (n < Npad){
      u16x4 pk;
      pk[0] = f2bf(t[kl+0][nl]); pk[1] = f2bf(t[kl+1][nl]);
      pk[2] = f2bf(t[kl+2][nl]); pk[3] = f2bf(t[kl+3][nl]);
      *(u16x4*)&op[(size_t)n*K + k0 + kl] = pk;
    }
  }
}

// ---------------- v-part of qkv -> vT[b,h][d][t] (bf16) ----------------
__global__ void vtrans_kernel(const u16* __restrict__ qkv, u16* __restrict__ vT){
  __shared__ u16 s[32][33];
  int bh = blockIdx.z; int b = bh/Hh, h = bh - b*Hh;
  int t0 = blockIdx.x*32, d0 = blockIdx.y*32;
  int tx=threadIdx.x, ty=threadIdx.y;       // block (32,8)
  #pragma unroll
  for (int i=0;i<4;i++)
    s[ty+i*8][tx] = qkv[(size_t)(b*Tt + t0+ty+i*8)*2304 + 1536 + h*64 + d0 + tx];
  __syncthreads();
  #pragma unroll
  for (int i=0;i<4;i++)
    vT[((size_t)bh*64 + d0+ty+i*8)*Tt + t0 + tx] = s[tx][ty+i*8];
}

// ---------------- bias concat [L][2304] ----------------
__global__ void bconcat_kernel(const float* __restrict__ bq, const float* __restrict__ bk,
                               const float* __restrict__ bv, float* __restrict__ o){
  int i = blockIdx.x*256 + threadIdx.x;
  if (i >= Ll*2304) return;
  int l = i/2304, j = i - l*2304;
  o[i] = (j < 768) ? bq[l*768+j] : (j < 1536) ? bk[l*768+j-768] : bv[l*768+j-1536];
}

// ---------------- flash attention, QB=64 ----------------
__global__ __launch_bounds__(256) void flash_kernel(
    const u16* __restrict__ qkv, const u16* __restrict__ vT, u16* __restrict__ y){
  __shared__ u16 Ks[2][64*64];     // [s][k], 128B rows, XOR-swizzled
  __shared__ u16 Vs[2][64*64];     // [d][s], 128B rows, XOR-swizzled
  __shared__ u16 Ps[4][16*64];     // per-wave [q][s], 128B rows, XOR-swizzled
  int bx = blockIdx.x;
  int bh = blockIdx.y; int b = bh/Hh, h = bh - b*Hh;
  int q0 = bx*64;
  int tid = threadIdx.x, lane = tid&63, wid = tid>>6;
  const size_t tokbase = (size_t)b*Tt;
  int arow = lane&15, akof = (lane>>4)*8;
  bf16x8 qa[2];
  #pragma unroll
  for (int ks=0;ks<2;ks++)
    qa[ks] = *(const bf16x8*)&qkv[(tokbase + q0 + wid*16 + arow)*2304
                                  + h*64 + ks*32 + akof];
  int srow = lane>>3;
  int sbyte = ((lane&7)*16) ^ (srow<<4);
  const u16* kbase = qkv + tokbase*2304 + 768 + h*64;
  const u16* vbase = vT + (size_t)bh*64*Tt;
  auto STAGEKV = [&](int t, int bb){
    int j0 = t*64;
    #pragma unroll
    for (int c=0;c<2;c++){
      int r = wid*16 + c*8 + srow;
      GL16(kbase + (size_t)(j0 + r)*2304 + (sbyte>>1), &Ks[bb][(wid*16 + c*8)*64]);
      GL16(vbase + (size_t)r*Tt + j0 + (sbyte>>1),     &Vs[bb][(wid*16 + c*8)*64]);
    }
  };
  float m_r[4], l_r[4];
  f32x4 o_acc[4] = {};
  #pragma unroll
  for (int jj=0;jj<4;jj++){ m_r[jj] = -1e30f; l_r[jj] = 0.f; }

  int njt = bx + 1;
  STAGEKV(0, 0);
  asm volatile("s_waitcnt vmcnt(0)" ::: "memory");
  __builtin_amdgcn_s_barrier();
  for (int t=0; t<njt; t++){
    int cur = t&1;
    if (t+1 < njt) STAGEKV(t+1, cur^1);
    int j0 = t*64;
    f32x4 sacc[4] = {};
    #pragma unroll
    for (int ks=0;ks<2;ks++){
      bf16x8 kf[4];
      #pragma unroll
      for (int ni=0;ni<4;ni++){
        int s16 = ni*16 + (lane&15);
        int kb = (ks*64 + (lane>>4)*16) ^ ((s16&7)<<4);
        kf[ni] = *(const bf16x8*)((const char*)&Ks[cur][0] + s16*128 + kb);
      }
      #pragma unroll
      for (int ni=0;ni<4;ni++)
        sacc[ni] = __builtin_amdgcn_mfma_f32_16x16x32_bf16(qa[ks], kf[ni], sacc[ni], 0,0,0);
    }
    float tmax[4];
    #pragma unroll
    for (int jj=0;jj<4;jj++) tmax[jj] = -1e30f;
    #pragma unroll
    for (int ni=0;ni<4;ni++)
      #pragma unroll
      for (int jj=0;jj<4;jj++){
        float v = sacc[ni][jj]*0.125f;
        int sg = j0 + ni*16 + (lane&15);
        int tg = q0 + wid*16 + (lane>>4)*4 + jj;
        v = (sg <= tg) ? v : -1e30f;
        sacc[ni][jj] = v;
        tmax[jj] = fmaxf(tmax[jj], v);
      }
    #pragma unroll
    for (int jj=0;jj<4;jj++){
      float tm = tmax[jj];
      tm = fmaxf(tm, __shfl_xor(tm,1)); tm = fmaxf(tm, __shfl_xor(tm,2));
      tm = fmaxf(tm, __shfl_xor(tm,4)); tm = fmaxf(tm, __shfl_xor(tm,8));
      float mn = fmaxf(m_r[jj], tm);
      float al = __expf(m_r[jj] - mn);
      m_r[jj] = mn;
      l_r[jj] *= al;
      tmax[jj] = al;           // reuse as alpha
    }
    float tsum[4] = {};
    #pragma unroll
    for (int ni=0;ni<4;ni++)
      #pragma unroll
      for (int jj=0;jj<4;jj++){
        float p = __expf(sacc[ni][jj] - m_r[jj]);
        tsum[jj] += p;
        int pr = (lane>>4)*4 + jj;
        int pcb = (2*(ni*16 + (lane&15))) ^ ((pr&7)<<4);
        *(u16*)((char*)&Ps[wid][0] + pr*128 + pcb) = f2bf(p);
      }
    #pragma unroll
    for (int jj=0;jj<4;jj++){
      float ts = tsum[jj];
      ts += __shfl_xor(ts,1); ts += __shfl_xor(ts,2);
      ts += __shfl_xor(ts,4); ts += __shfl_xor(ts,8);
      l_r[jj] += ts;
      float al = tmax[jj];
      #pragma unroll
      for (int ni2=0;ni2<4;ni2++) o_acc[ni2][jj] *= al;
    }
    #pragma unroll
    for (int ks2=0;ks2<2;ks2++){
      bf16x8 pa, vf[4];
      int prr = lane&15;
      int pb = (ks2*64 + (lane>>4)*16) ^ ((prr&7)<<4);
      pa = *(const bf16x8*)((const char*)&Ps[wid][0] + prr*128 + pb);
      #pragma unroll
      for (int ni2=0;ni2<4;ni2++){
        int d16 = ni2*16 + (lane&15);
        int sb = (ks2*64 + (lane>>4)*16) ^ ((d16&7)<<4);
        vf[ni2] = *(const bf16x8*)((const char*)&Vs[cur][0] + d16*128 + sb);
      }
      #pragma unroll
      for (int ni2=0;ni2<4;ni2++)
        o_acc[ni2] = __builtin_amdgcn_mfma_f32_16x16x32_bf16(pa, vf[ni2], o_acc[ni2], 0,0,0);
    }
    asm volatile("s_waitcnt vmcnt(0) lgkmcnt(0)" ::: "memory");
    __builtin_amdgcn_s_barrier();
  }
  #pragma unroll
  for (int jj=0;jj<4;jj++){
    float inv = 1.0f / l_r[jj];
    int tok2 = q0 + wid*16 + (lane>>4)*4 + jj;
    size_t rb = (tokbase + tok2)*Cc + h*64;
    #pragma unroll
    for (int ni2=0;ni2<4;ni2++)
      y[rb + ni2*16 + (lane&15)] = f2bf(o_acc[ni2][jj] * inv);
  }
}

// -------- MFMA GEMM: BMxBN tile, BK=64, 128B swizzled LDS rows (T2) --------
// LDS[row][chunk] = global[row][chunk ^ (row&7)]  (16B chunks; linear gload_lds dest,
// pre-swizzled global source; ds_read applies the same XOR) -> conflict-free b128.
// NBUF=2: stage(t+1)->compute(t)->drain. NBUF=3: counted vmcnt(LOADS).
template<int NBUF, int BM, int BN, bool BIAS, bool RESID, bool GELU, bool OUTBF, bool ROWSCAN>
__global__ __launch_bounds__(256) void mm_kernel(
    const u16* __restrict__ A, const u16* __restrict__ Bm,
    const float* __restrict__ bias, const float* __restrict__ resid,
    void* __restrict__ out, int N, int K, int lda, int ldb, int ldc)
{
  constexpr int FM   = BM/32;
  constexpr int FN   = BN/32;
  constexpr int CPW  = FN*16;
  constexpr int ESTR = CPW + 4;
  constexpr int ABUF = BM*64;          // u16 elems per A buffer (rows of 64 = 128B)
  constexpr int BBUF = BN*64;
  constexpr int ACALLS = BM/32;        // GL16 calls per wave (8 rows each)
  constexpr int BCALLS = BN/32;
  constexpr int LOADS = ACALLS + BCALLS;
  constexpr int SMEM_STAGE = NBUF*(ABUF+BBUF)*2;
  constexpr int SMEM_EPI   = 4*16*ESTR*4;
  constexpr int SMEMB = SMEM_STAGE > SMEM_EPI ? SMEM_STAGE : SMEM_EPI;
  __shared__ __align__(16) char smem[SMEMB];
  u16* As = (u16*)smem;
  u16* Bs = As + NBUF*ABUF;

  int bx = blockIdx.x, by = blockIdx.y;
  {                                    // bijective XCD swizzle (m204)
    int gx = gridDim.x;
    int nwg = gx * gridDim.y;
    int flat = by*gx + bx;
    int qq = nwg >> 3, rr = nwg & 7;
    int xcd = flat & 7, lid = flat >> 3;
    int swz = (xcd < rr) ? xcd*(qq+1) + lid : rr*(qq+1) + (xcd-rr)*qq + lid;
    bx = swz % gx; by = swz / gx;
  }
  int m0 = bx*BM, n0 = by*BN;
  int tid = threadIdx.x, lane = tid & 63, wid = tid >> 6;
  int wr = wid >> 1, wc = wid & 1;
  int r0 = wr*(BM/2), c0 = wc*(BN/2);
  int lrow = lane & 15;
  // staging source: row_local = wid*(BM/4)+c*8+(lane>>3); elem = ((lane&7)^(lane>>3))*8
  int sswz = ((lane & 7) ^ (lane >> 3)) * 8;
  const u16* Ap = A + (size_t)(m0 + wid*(BM/4) + (lane>>3))*lda + sswz;
  const u16* Bp = Bm + (size_t)(n0 + wid*(BN/4) + (lane>>3))*ldb + sswz;
  // fragment-read chunk offsets (bytes): chunk' = (ks*4 + lane>>4) ^ (lane&7)
  int cof0 = (((lane>>4)    ) ^ (lane&7)) << 4;
  int cof1 = (((lane>>4) + 4) ^ (lane&7)) << 4;
  int nt = K/64;
  auto STAGE = [&](int t, int bb){
    int kk = t*64;
    u16* Albase = As + bb*ABUF + (wid*(BM/4))*64;
    #pragma unroll
    for (int c=0;c<ACALLS;c++)
      GL16(Ap + kk + (size_t)(c*8)*lda, Albase + c*512);
    u16* Blbase = Bs + bb*BBUF + (wid*(BN/4))*64;
    #pragma unroll
    for (int c=0;c<BCALLS;c++)
      GL16(Bp + kk + (size_t)(c*8)*ldb, Blbase + c*512);
  };
  f32x4 acc[FM][FN] = {};
  if constexpr (NBUF==2){
    STAGE(0, 0);
    WAITVM(0);
    __builtin_amdgcn_s_barrier();
  } else {
    STAGE(0, 0);
    if (nt > 1) STAGE(1, 1);
    WAITVM(LOADS);
    __builtin_amdgcn_s_barrier();
  }
  for (int t = 0; t < nt; t++){
    int bb = (NBUF==2) ? (t & 1) : (t % 3);
    if constexpr (NBUF==2){
      if (t+1 < nt) STAGE(t+1, (t+1)&1);
    } else {
      if (t+2 < nt) STAGE(t+2, (t+2)%3);
    }
    const char* Ab2 = (const char*)(As + bb*ABUF);
    const char* Bb2 = (const char*)(Bs + bb*BBUF);
    #pragma unroll
    for (int ks=0;ks<2;ks++){
      int cof = ks ? cof1 : cof0;
      bf16x8 af[FM], bfr[FN];
      #pragma unroll
      for (int m=0;m<FM;m++) af[m] = *(const bf16x8*)(Ab2 + (r0 + m*16 + lrow)*128 + cof);
      #pragma unroll
      for (int n=0;n<FN;n++) bfr[n] = *(const bf16x8*)(Bb2 + (c0 + n*16 + lrow)*128 + cof);
      #pragma unroll
      for (int m=0;m<FM;m++)
        #pragma unroll
        for (int n=0;n<FN;n++)
          acc[m][n] = __builtin_amdgcn_mfma_f32_16x16x32_bf16(af[m], bfr[n], acc[m][n], 0,0,0);
    }
    if constexpr (NBUF==2){
      asm volatile("s_waitcnt vmcnt(0) lgkmcnt(0)" ::: "memory");
    } else {
      if (t+2 < nt) WAITVM(LOADS); else WAITVM(0);
    }
    __builtin_amdgcn_s_barrier();
  }

  // ---- epilogue: per-wave-private LDS transpose tile, coalesced stores ----
  float* ebuf = (float*)smem + wid*16*ESTR;
  int er = lane >> 2;
  int ec = (lane & 3) * (CPW/4);
  #pragma unroll
  for (int m=0;m<FM;m++){
    #pragma unroll
    for (int n=0;n<FN;n++)
      #pragma unroll
      for (int j=0;j<4;j++)
        ebuf[((lane>>4)*4+j)*ESTR + n*16 + (lane&15)] = acc[m][n][j];
    __builtin_amdgcn_s_waitcnt(0);     // lgkm drain for own-wave LDS RAW
    if constexpr (ROWSCAN){
      // fp32 out, arbitrary ldc; logits never re-read -> nontemporal stores
      #pragma unroll
      for (int rr2=0; rr2<16; rr2++){
        int gr2 = m0 + r0 + m*16 + rr2;
        int gc2 = n0 + c0 + lane;
        float v = ebuf[rr2*ESTR + lane];
        if (gc2 < N)
          __builtin_nontemporal_store(v, &((float*)out)[(size_t)gr2*ldc + gc2]);
      }
    } else {
      int grow = m0 + r0 + m*16 + er;
      int gcol = n0 + c0 + ec;
      size_t rbase = (size_t)grow*ldc;
      if constexpr (OUTBF){
        u16 tmp[CPW/4];
        #pragma unroll
        for (int q=0;q<FN;q++){
          float4 v = *(const float4*)&ebuf[er*ESTR + ec + q*4];
          float f0=v.x, f1=v.y, f2=v.z, f3=v.w;
          if (BIAS){
            float4 b4 = *(const float4*)&bias[gcol + q*4];
            f0+=b4.x; f1+=b4.y; f2+=b4.z; f3+=b4.w;
          }
          if (GELU){
            f0 = 0.5f*f0*(1.f+erff(f0*0.70710678118654752f));
            f1 = 0.5f*f1*(1.f+erff(f1*0.70710678118654752f));
            f2 = 0.5f*f2*(1.f+erff(f2*0.70710678118654752f));
            f3 = 0.5f*f3*(1.f+erff(f3*0.70710678118654752f));
          }
          tmp[q*4+0]=f2bf(f0); tmp[q*4+1]=f2bf(f1);
          tmp[q*4+2]=f2bf(f2); tmp[q*4+3]=f2bf(f3);
        }
        #pragma unroll
        for (int s2=0; s2<CPW/32; s2++)
          *(u16x8*)&((u16*)out)[rbase + gcol + s2*8] = *(const u16x8*)&tmp[s2*8];
      } else {
        #pragma unroll
        for (int q=0;q<FN;q++){
          float4 v = *(const float4*)&ebuf[er*ESTR + ec + q*4];
          float f0=v.x, f1=v.y, f2=v.z, f3=v.w;
          if (BIAS){
            float4 b4 = *(const float4*)&bias[gcol + q*4];
            f0+=b4.x; f1+=b4.y; f2+=b4.z; f3+=b4.w;
          }
          if (GELU){
            f0 = 0.5f*f0*(1.f+erff(f0*0.70710678118654752f));
            f1 = 0.5f*f1*(1.f+erff(f1*0.70710678118654752f));
            f2 = 0.5f*f2*(1.f+erff(f2*0.70710678118654752f));
            f3 = 0.5f*f3*(1.f+erff(f3*0.70710678118654752f));
          }
          if (RESID){
            float4 r4 = *(const float4*)&resid[rbase + gcol + q*4];
            f0+=r4.x; f1+=r4.y; f2+=r4.z; f3+=r4.w;
          }
          float4 o4; o4.x=f0; o4.y=f1; o4.z=f2; o4.w=f3;
          *(float4*)&((float*)out)[rbase + gcol + q*4] = o4;
        }
      }
    }
  }
}

// ---------------- orchestration ----------------
extern "C" void kernel_launch(void* const* d_in, const int* in_sizes, int n_in,
                              void* d_out, int out_size, void* d_ws, size_t ws_size,
                              hipStream_t stream){
  const int*   idx  = (const int*)d_in[0];
  const float* tok  = (const float*)d_in[1];
  const float* pos  = (const float*)d_in[2];
  const float* ln1g = (const float*)d_in[3];
  const float* ln1b = (const float*)d_in[4];
  const float* Wq   = (const float*)d_in[5];
  const float* bq   = (const float*)d_in[6];
  const float* Wk   = (const float*)d_in[7];
  const float* bk   = (const float*)d_in[8];
  const float* Wv   = (const float*)d_in[9];
  const float* bv   = (const float*)d_in[10];
  const float* Wp   = (const float*)d_in[11];
  const float* bp   = (const float*)d_in[12];
  const float* ln2g = (const float*)d_in[13];
  const float* ln2b = (const float*)d_in[14];
  const float* Wf1  = (const float*)d_in[15];
  const float* bf1  = (const float*)d_in[16];
  const float* Wf2  = (const float*)d_in[17];
  const float* bf2  = (const float*)d_in[18];
  const float* lnfg = (const float*)d_in[19];
  const float* lnfb = (const float*)d_in[20];
  const float* headW= (const float*)d_in[21];
  float* outp = (float*)d_out;

  char* w = (char*)d_ws;
  u16* wqkvT = (u16*)w;  w += (size_t)Ll*2304*768*2;
  u16* wpT   = (u16*)w;  w += (size_t)Ll*768*768*2;
  u16* wf1T  = (u16*)w;  w += (size_t)Ll*3072*768*2;
  u16* wf2T  = (u16*)w;  w += (size_t)Ll*768*3072*2;
  u16* headT = (u16*)w;  w += (size_t)VPAD*768*2;
  float* bqkv= (float*)w;w += (size_t)Ll*2304*4;
  float* x   = (float*)w;w += (size_t)NTOK*Cc*4;
  u16* h     = (u16*)w;  w += (size_t)NTOK*Cc*2;
  u16* qkv   = (u16*)w;  w += (size_t)NTOK*2304*2;
  u16* vT    = (u16*)w;  w += (size_t)Bsz*Hh*64*Tt*2;
  u16* y     = (u16*)w;  w += (size_t)NTOK*Cc*2;
  u16* ff    = (u16*)w;  w += (size_t)NTOK*4*Cc*2;

  dim3 tb(32,8);
  wtrans_kernel<<<dim3(24,12,Ll), tb, 0, stream>>>(Wq, wqkvT,          768, 768, 768, (size_t)Cc*Cc, (size_t)2304*768);
  wtrans_kernel<<<dim3(24,12,Ll), tb, 0, stream>>>(Wk, wqkvT+768*768,  768, 768, 768, (size_t)Cc*Cc, (size_t)2304*768);
  wtrans_kernel<<<dim3(24,12,Ll), tb, 0, stream>>>(Wv, wqkvT+1536*768, 768, 768, 768, (size_t)Cc*Cc, (size_t)2304*768);
  wtrans_kernel<<<dim3(24,12,Ll), tb, 0, stream>>>(Wp, wpT,            768, 768, 768, (size_t)Cc*Cc, (size_t)768*768);
  wtrans_kernel<<<dim3(96,12,Ll), tb, 0, stream>>>(Wf1, wf1T,          768, 3072, 3072, (size_t)Cc*4*Cc, (size_t)3072*768);
  wtrans_kernel<<<dim3(24,48,Ll), tb, 0, stream>>>(Wf2, wf2T,          3072, 768, 768, (size_t)4*Cc*Cc, (size_t)768*3072);
  wtrans_kernel<<<dim3(VPAD/32,12,1), tb, 0, stream>>>(headW, headT, 768, Vv, VPAD, 0, 0);
  bconcat_kernel<<<(Ll*2304+255)/256, 256, 0, stream>>>(bq, bk, bv, bqkv);

  embed_kernel<<<NTOK*(Cc/4)/256, 256, 0, stream>>>(idx, tok, pos, x);

  for (int l=0;l<Ll;l++){
    ln_kernel<<<NTOK, 256, 0, stream>>>(x, ln1g+l*Cc, ln1b+l*Cc, h);
    mm_kernel<2,64,128,true,false,false,true,false><<<dim3(32,18,1), 256, 0, stream>>>(
        h, wqkvT+(size_t)l*2304*768, bqkv+l*2304, nullptr, qkv, 2304, 768, 768, 768, 2304);
    vtrans_kernel<<<dim3(32,2,Bsz*Hh), tb, 0, stream>>>(qkv, vT);
    flash_kernel<<<dim3(Tt/64, Bsz*Hh), 256, 0, stream>>>(qkv, vT, y);
    mm_kernel<3,64,64,true,true,false,false,false><<<dim3(32,12,1), 256, 0, stream>>>(
        y, wpT+(size_t)l*768*768, bp+l*Cc, x, x, 768, 768, 768, 768, 768);
    ln_kernel<<<NTOK, 256, 0, stream>>>(x, ln2g+l*Cc, ln2b+l*Cc, h);
    mm_kernel<2,64,128,true,false,true,true,false><<<dim3(32,24,1), 256, 0, stream>>>(
        h, wf1T+(size_t)l*3072*768, bf1+(size_t)l*4*Cc, nullptr, ff, 3072, 768, 768, 768, 3072);
    mm_kernel<3,64,64,true,true,false,false,false><<<dim3(32,12,1), 256, 0, stream>>>(
        ff, wf2T+(size_t)l*768*3072, bf2+l*Cc, x, x, 768, 3072, 3072, 3072, 768);
  }
  ln_kernel<<<NTOK, 256, 0, stream>>>(x, lnfg, lnfb, h);
  mm_kernel<2,128,128,false,false,false,false,true><<<dim3(16,VPAD/128,1), 256, 0, stream>>>(
      h, headT, nullptr, nullptr, outp, Vv, 768, 768, 768, Vv);
}